// Round 5
// baseline (809.411 us; speedup 1.0000x reference)
//
#include <hip/hip_runtime.h>

// YOLO_GNN on MI355X — round 5: balanced conv staging (768 uniform items) +
// expert layer1 re-split over f-chunks (1024 blocks) for gather bandwidth.
// prep -> convfused -> mid -> h1part(x8) -> expert2 -> out.

typedef float f32x4 __attribute__((ext_vector_type(4)));

// ---------------- prep: zero pooled; transpose conv weights ----------------
__global__ void k_prep(const float* __restrict__ w1, const float* __restrict__ w2,
                       float* __restrict__ wt1, float* __restrict__ wt2,
                       float* __restrict__ pooled) {
    int i = blockIdx.x * 256 + threadIdx.x;
    if (i < 4096) pooled[i] = 0.f;
    if (i < 864) {            // conv1: 32 co x 27 k -> [k][co]
        int k = i >> 5, co = i & 31;
        wt1[i] = w1[co * 27 + k];
    }
    if (i < 18432) {          // conv2: ((ky*32+ci)*3+kx)*64+co
        int co = i & 63, tt = i >> 6;
        int kx = tt % 3, u = tt / 3;
        int ci = u & 31, ky = u >> 5;
        wt2[i] = w2[co * 288 + ci * 9 + ky * 3 + kx];
    }
}

// ---------------- fused conv1+ReLU -> LDS -> conv2+ReLU -> GAP ----------------
// Block = one conv2 row (oy) of image b; 256 threads = 4 waves.
// Staging: 768 items = ch(2) x r(3) x 128 px-slots (114 real) — each thread
// exactly 3 items; ch/r wave-uniform by construction (i = t + k*256).
__global__ __launch_bounds__(256) void k_convfused(const float* __restrict__ x,
                                                   const float* __restrict__ wt1,
                                                   const float* __restrict__ b1,
                                                   const float* __restrict__ wt2,
                                                   const float* __restrict__ b2,
                                                   float* __restrict__ pooled) {
    __shared__ float s[32][3][57][2];   // [ci][row][half][par], 43776 B
    int oy = blockIdx.x;                // 0..55
    int b = blockIdx.y;                 // 0..63
    const float* xb = x + (size_t)b * 3 * 224 * 224;
    int tid = threadIdx.x;

#pragma unroll 1
    for (int k = 0; k < 3; k++) {
        int i = tid + k * 256;
        int ch = i / 384;               // co half (16 ch) — wave-uniform
        int rem = i - ch * 384;
        int r = rem >> 7;               // row 0..2 — wave-uniform
        int px = rem & 127;             // 0..127, valid < 114
        if (px < 114) {
            int iy = 2 * oy + r;
            if (iy < 112 && px < 112) {
                float acc[16];
#pragma unroll
                for (int j = 0; j < 16; j++) acc[j] = 0.f;
#pragma unroll
                for (int ci = 0; ci < 3; ci++) {
                    float xv[9];        // 9 independent loads per channel
#pragma unroll
                    for (int ky = 0; ky < 3; ky++) {
                        int yy = 2 * iy + ky;
#pragma unroll
                        for (int kx = 0; kx < 3; kx++) {
                            int xx = 2 * px + kx;
                            bool ok = (yy < 224) && (xx < 224);   // SAME: pad hi only
                            xv[ky * 3 + kx] = ok ? xb[((size_t)ci * 224 + yy) * 224 + xx] : 0.f;
                        }
                    }
#pragma unroll
                    for (int k9 = 0; k9 < 9; k9++) {
                        const float* w = wt1 + (ci * 9 + k9) * 32 + ch * 16;  // uniform
#pragma unroll
                        for (int j = 0; j < 16; j++) acc[j] = fmaf(xv[k9], w[j], acc[j]);
                    }
                }
#pragma unroll
                for (int j = 0; j < 16; j++)
                    s[ch * 16 + j][r][px >> 1][px & 1] = fmaxf(acc[j] + b1[ch * 16 + j], 0.f);
            } else {
#pragma unroll
                for (int j = 0; j < 16; j++)
                    s[ch * 16 + j][r][px >> 1][px & 1] = 0.f;
            }
        }
    }
    __syncthreads();

    // ---- conv2: wave q -> co [16q,16q+16); lane -> opx ----
    int q = __builtin_amdgcn_readfirstlane((int)(tid >> 6));
    int lane = tid & 63;
    bool pvld = lane < 56;
    int opx = pvld ? lane : 55;
    float acc[16];
#pragma unroll
    for (int j = 0; j < 16; j++) acc[j] = 0.f;
#pragma unroll
    for (int ky = 0; ky < 3; ky++) {
#pragma unroll 4
        for (int ci = 0; ci < 32; ci++) {
            float2 v01 = *(const float2*)&s[ci][ky][opx][0];     // kx=0,1
            float v2 = s[ci][ky][opx + 1][0];                    // kx=2
            const float* w = wt2 + ((ky * 32 + ci) * 3) * 64 + q * 16;  // uniform
#pragma unroll
            for (int j = 0; j < 16; j++) acc[j] = fmaf(v01.x, w[j], acc[j]);
#pragma unroll
            for (int j = 0; j < 16; j++) acc[j] = fmaf(v01.y, w[64 + j], acc[j]);
#pragma unroll
            for (int j = 0; j < 16; j++) acc[j] = fmaf(v2, w[128 + j], acc[j]);
        }
    }
#pragma unroll
    for (int j = 0; j < 16; j++) {
        float rv = pvld ? fmaxf(acc[j] + b2[q * 16 + j], 0.f) : 0.f;
#pragma unroll
        for (int sft = 32; sft > 0; sft >>= 1) rv += __shfl_xor(rv, sft);
        if (lane == 0) atomicAdd(&pooled[b * 64 + q * 16 + j], rv);
    }
}

// ---------------- mid: feats -> logits -> top2 -> graph(cm,dropped) -> agg ----------------
__global__ __launch_bounds__(256) void k_mid(const float* __restrict__ pooled,
                                             const float* __restrict__ fcf_w,
                                             const float* __restrict__ fcf_b,
                                             const float* __restrict__ fcc_w,
                                             const float* __restrict__ fcc_b,
                                             int* __restrict__ top_idx,
                                             float* __restrict__ cm,
                                             int* __restrict__ dropped,
                                             float* __restrict__ agg) {
    __shared__ float sf[1024];
    __shared__ float slog[2][80];
    __shared__ float sr[10][4];
    __shared__ float sAn[25];
    int b = blockIdx.x, t = threadIdx.x;

    {   // feats = relu(pooled/3136 @ fcf_w + fcf_b)
        float acc[4];
#pragma unroll
        for (int j = 0; j < 4; j++) acc[j] = fcf_b[t + j * 256];
        for (int cc = 0; cc < 64; cc++) {
            float pv = pooled[b * 64 + cc] * (1.f / 3136.f);    // uniform
#pragma unroll
            for (int j = 0; j < 4; j++)
                acc[j] = fmaf(pv, fcf_w[cc * 1024 + t + j * 256], acc[j]);
        }
#pragma unroll
        for (int j = 0; j < 4; j++) sf[t + j * 256] = fmaxf(acc[j], 0.f);
    }
    __syncthreads();

    if (t < 160) {      // logits halves: c=t%80, half=t/80 over 512 f each
        int c = t % 80, half = t / 80;
        float acc = half ? 0.f : fcc_b[c];
        for (int f = half * 512; f < half * 512 + 512; f++)
            acc = fmaf(sf[f], fcc_w[f * 80 + c], acc);
        slog[half][c] = acc;
    }
    {   // graph quarter norms/dots
        float q1 = sf[t], q2 = sf[256 + t], q3 = sf[512 + t], q4 = sf[768 + t];
        float part[10] = {q1 * q1, q2 * q2, q3 * q3, q4 * q4,
                          q1 * q2, q1 * q3, q1 * q4, q2 * q3, q2 * q4, q3 * q4};
        int lane = t & 63, wid = t >> 6;
#pragma unroll
        for (int i = 0; i < 10; i++) {
            float r = part[i];
#pragma unroll
            for (int sft = 32; sft > 0; sft >>= 1) r += __shfl_xor(r, sft);
            if (lane == 0) sr[i][wid] = r;
        }
    }
    __syncthreads();

    if (t < 64) {       // top2 via wave butterfly (tie: lower index)
        int ln = t;
        float vA = slog[0][ln] + slog[1][ln];
        int iA = ln;
        bool hasB = ln < 16;
        float vB = hasB ? slog[0][64 + ln] + slog[1][64 + ln] : -3.4e38f;
        int iB = hasB ? 64 + ln : 0x7fffffff;
        float v1, v2; int i1, i2;
        if (vB > vA) { v1 = vB; i1 = iB; v2 = vA; i2 = iA; }
        else         { v1 = vA; i1 = iA; v2 = vB; i2 = iB; }
#pragma unroll
        for (int m = 1; m < 64; m <<= 1) {
            float o1 = __shfl_xor(v1, m), o2 = __shfl_xor(v2, m);
            int oi1 = __shfl_xor(i1, m), oi2 = __shfl_xor(i2, m);
            bool selfWins = (v1 > o1) || (v1 == o1 && i1 < oi1);
            float n1, n2; int ni1, ni2;
            if (selfWins) {
                n1 = v1; ni1 = i1;
                bool s2 = (v2 > o1) || (v2 == o1 && i2 < oi1);
                n2 = s2 ? v2 : o1; ni2 = s2 ? i2 : oi1;
            } else {
                n1 = o1; ni1 = oi1;
                bool s2 = (v1 > o2) || (v1 == o2 && i1 < oi2);
                n2 = s2 ? v1 : o2; ni2 = s2 ? i1 : oi2;
            }
            v1 = n1; i1 = ni1; v2 = n2; i2 = ni2;
        }
        if (ln == 0) { top_idx[b * 2] = i1; top_idx[b * 2 + 1] = i2; }
    }
    if (t == 0) {       // graph: d2 -> knn -> An(LDS), cm, dropped
        float tot[10];
#pragma unroll
        for (int i = 0; i < 10; i++) tot[i] = sr[i][0] + sr[i][1] + sr[i][2] + sr[i][3];
        float n_[5] = {0.f, tot[0], tot[1], tot[2], tot[3]};
        float dd[5][5];
        dd[1][1] = tot[0]; dd[2][2] = tot[1]; dd[3][3] = tot[2]; dd[4][4] = tot[3];
        dd[1][2] = dd[2][1] = tot[4]; dd[1][3] = dd[3][1] = tot[5];
        dd[1][4] = dd[4][1] = tot[6]; dd[2][3] = dd[3][2] = tot[7];
        dd[2][4] = dd[4][2] = tot[8]; dd[3][4] = dd[4][3] = tot[9];
        float Q = tot[0] + tot[1] + tot[2] + tot[3];
        float d2[5][5];
        d2[0][0] = 0.f;
        for (int i = 1; i < 5; i++) {
            float v = Q + n_[i] - 2.f * dd[1][i];
            d2[0][i] = v; d2[i][0] = v;
        }
        for (int i = 1; i < 5; i++)
            for (int j = 1; j < 5; j++)
                d2[i][j] = (i == j) ? 0.f : (n_[i] + n_[j] - 2.f * dd[i][j]);
        int drp[5];
        for (int r = 0; r < 5; r++) {
            int dm = 0; float vm = d2[r][0];
            for (int ss = 1; ss < 5; ss++)
                if (d2[r][ss] >= vm) { vm = d2[r][ss]; dm = ss; }
            drp[r] = dm;
            dropped[b * 5 + r] = dm;
        }
        float dinv[5], Ah[5][5];
        for (int r = 0; r < 5; r++) {
            float dsum = 0.f;
            for (int ss = 0; ss < 5; ss++) {
                float a = ((ss != drp[r]) ? 1.f : 0.f) + ((ss == r) ? 1.f : 0.f);
                Ah[r][ss] = a; dsum += a;
            }
            dinv[r] = dsum > 0.f ? 1.f / sqrtf(dsum) : 0.f;
        }
        float colsum[5] = {0.f, 0.f, 0.f, 0.f, 0.f};
        for (int r = 0; r < 5; r++)
            for (int ss = 0; ss < 5; ss++) {
                float v = Ah[r][ss] * dinv[r] * dinv[ss];
                sAn[r * 5 + ss] = v;
                colsum[ss] += v;
            }
        for (int ss = 0; ss < 5; ss++) cm[b * 5 + ss] = colsum[ss] * 0.2f;
    }
    __syncthreads();

    // agg = An @ Xg
    for (int f = t; f < 1024; f += 256) {
        float a0 = sf[f];
        bool inq = f < 256;
        float v1 = 0.f, v2 = 0.f, v3 = 0.f, v4 = 0.f;
        if (inq) { v1 = sf[f]; v2 = sf[256 + f]; v3 = sf[512 + f]; v4 = sf[768 + f]; }
#pragma unroll
        for (int tt = 0; tt < 5; tt++) {
            float r = sAn[tt * 5] * a0;
            if (inq)
                r += sAn[tt * 5 + 1] * v1 + sAn[tt * 5 + 2] * v2 +
                     sAn[tt * 5 + 3] * v3 + sAn[tt * 5 + 4] * v4;
            agg[((size_t)b * 5 + tt) * 1024 + f] = r;
        }
    }
}

// ---------------- expert layer1 partials: h1part[fc][pair][t][h] (1024 blocks) ----------------
__global__ __launch_bounds__(128) void k_h1part(const float* __restrict__ agg,
                                                const float* __restrict__ w1,
                                                const int* __restrict__ top_idx,
                                                float* __restrict__ h1part) {
    int pair = blockIdx.x;              // 128
    int fc = blockIdx.y;                // 8 chunks of 128 f
    int hg = threadIdx.x;               // h = 4*hg
    int bsm = pair >> 1;
    int c = top_idx[pair];
    const f32x4* wv = (const f32x4*)(w1 + (size_t)c * 1024 * 512);
    const f32x4* av = (const f32x4*)(agg + (size_t)bsm * 5 * 1024);
    f32x4 acc[5];
#pragma unroll
    for (int t = 0; t < 5; t++) acc[t] = (f32x4)(0.f);
    int f0 = fc * 128;
#pragma unroll 2
    for (int f4 = 0; f4 < 32; f4++) {
        f32x4 a[5];
#pragma unroll
        for (int t = 0; t < 5; t++) a[t] = av[t * 256 + fc * 32 + f4];  // uniform
#pragma unroll
        for (int j = 0; j < 4; j++) {
            f32x4 w = wv[(size_t)(f0 + f4 * 4 + j) * 128 + hg];         // 16B coalesced
#pragma unroll
            for (int t = 0; t < 5; t++) acc[t] += a[t][j] * w;
        }
    }
    float* op = h1part + (((size_t)fc * 128 + pair) * 5) * 512;
#pragma unroll
    for (int t = 0; t < 5; t++)
        *(f32x4*)(op + t * 512 + 4 * hg) = acc[t];
}

// ---------------- expert2: fold + relu/cm + layer2 + b2 + @fin_w ----------------
__global__ __launch_bounds__(256) void k_expert2(const float* __restrict__ h1part,
                                                 const float* __restrict__ b1,
                                                 const float* __restrict__ w2,
                                                 const float* __restrict__ b2,
                                                 const float* __restrict__ finw,
                                                 const float* __restrict__ cm,
                                                 const int* __restrict__ top_idx,
                                                 float* __restrict__ M) {
    __shared__ float sp[512];
    __shared__ float sgq[4 * 256];
    __shared__ float sgg[256];
    int pair = blockIdx.x, t = threadIdx.x;
    int bsm = pair >> 1;
    int c = top_idx[pair];

    // fold: p[h] = sum_t cm[t]*relu(sum_fc part + b1)  — h = t, t+256
#pragma unroll
    for (int rep = 0; rep < 2; rep++) {
        int h = t + rep * 256;
        float pv = 0.f;
#pragma unroll
        for (int tt = 0; tt < 5; tt++) {
            float sv = 0.f;
#pragma unroll
            for (int fc = 0; fc < 8; fc++)
                sv += h1part[(((size_t)fc * 128 + pair) * 5 + tt) * 512 + h];
            float hv = fmaxf(sv + b1[c * 512 + h], 0.f);
            pv = fmaf(cm[bsm * 5 + tt], hv, pv);
        }
        sp[h] = pv;
    }
    __syncthreads();

    // layer 2: thread (og=t&63, hq=t>>6): f32x4 over its h-quarter
    {
        int og = t & 63, hq = t >> 6;
        const f32x4* wv2 = (const f32x4*)(w2 + (size_t)c * 512 * 256);
        f32x4 acc2 = (f32x4)(0.f);
#pragma unroll 4
        for (int h = hq * 128; h < hq * 128 + 128; h++)
            acc2 += sp[h] * wv2[(size_t)h * 64 + og];            // sp broadcast
        *(f32x4*)&sgq[(hq * 64 + og) * 4] = acc2;
    }
    __syncthreads();
    if (t < 64) {
        f32x4 gsum = *(const f32x4*)&sgq[(0 * 64 + t) * 4];
#pragma unroll
        for (int hq = 1; hq < 4; hq++) gsum += *(const f32x4*)&sgq[(hq * 64 + t) * 4];
        gsum += *(const f32x4*)&b2[c * 256 + 4 * t];
        *(f32x4*)&sgg[4 * t] = gsum;
    }
    __syncthreads();
    if (t < 80) {       // M[pair] = g @ fin_w
        float acc3 = 0.f;
        for (int o = 0; o < 256; o++) acc3 = fmaf(sgg[o], finw[o * 80 + t], acc3);
        M[pair * 80 + t] = acc3;
    }
}

// ---------------- final GCN + mean over k ----------------
__global__ __launch_bounds__(128) void k_out(const float* __restrict__ M,
                                             const float* __restrict__ finb,
                                             const int* __restrict__ dropped,
                                             float* __restrict__ out) {
    int b = blockIdx.x;
    int c = threadIdx.x;
    if (c >= 80) return;
    float bias = finb[c];
    float r = 0.f;
#pragma unroll
    for (int k = 0; k < 2; k++) {
        int n = b * 2 + k;
        float fin;
        if (n < 5) {
            float s = 0.f;
            for (int m = 0; m < 5; m++) {
                float a = ((m != dropped[63 * 5 + n]) ? 1.f : 0.f) + ((m == n) ? 1.f : 0.f);
                s += a * M[m * 80 + c];
            }
            fin = s * 0.2f + bias;
        } else {
            fin = M[n * 80 + c] + bias;
        }
        r += fin;
    }
    out[b * 80 + c] = r * 0.5f;
}

extern "C" void kernel_launch(void* const* d_in, const int* in_sizes, int n_in,
                              void* d_out, int out_size, void* d_ws, size_t ws_size,
                              hipStream_t stream) {
    const float* x       = (const float*)d_in[0];
    const float* conv1_w = (const float*)d_in[1];
    const float* conv1_b = (const float*)d_in[2];
    const float* conv2_w = (const float*)d_in[3];
    const float* conv2_b = (const float*)d_in[4];
    const float* fcf_w   = (const float*)d_in[5];
    const float* fcf_b   = (const float*)d_in[6];
    const float* fcc_w   = (const float*)d_in[7];
    const float* fcc_b   = (const float*)d_in[8];
    const float* gnn_w1  = (const float*)d_in[9];
    const float* gnn_b1  = (const float*)d_in[10];
    const float* gnn_w2  = (const float*)d_in[11];
    const float* gnn_b2  = (const float*)d_in[12];
    const float* fin_w   = (const float*)d_in[13];
    const float* fin_b   = (const float*)d_in[14];
    float* out = (float*)d_out;

    char* ws = (char*)d_ws;
    size_t off = 0;
    auto alloc = [&](size_t bytes) {
        void* pp = ws + off;
        off = (off + bytes + 255) & ~(size_t)255;
        return pp;
    };
    float* wt1     = (float*)alloc(864 * 4);
    float* wt2     = (float*)alloc(18432 * 4);
    float* pooled  = (float*)alloc(4096 * 4);
    int*   top_idx = (int*)alloc(128 * 4);
    float* cm      = (float*)alloc(320 * 4);
    int*   dropped = (int*)alloc(320 * 4);
    float* agg     = (float*)alloc(327680 * 4);
    float* h1part  = (float*)alloc((size_t)2621440 * 4);   // 8*128*5*512
    float* Mm      = (float*)alloc(10240 * 4);
    (void)ws_size; (void)in_sizes; (void)n_in; (void)out_size;

    k_prep<<<72, 256, 0, stream>>>(conv1_w, conv2_w, wt1, wt2, pooled);
    k_convfused<<<dim3(56, 64), 256, 0, stream>>>(x, wt1, conv1_b, wt2, conv2_b, pooled);
    k_mid<<<64, 256, 0, stream>>>(pooled, fcf_w, fcf_b, fcc_w, fcc_b,
                                  top_idx, cm, dropped, agg);
    k_h1part<<<dim3(128, 8), 128, 0, stream>>>(agg, gnn_w1, top_idx, h1part);
    k_expert2<<<128, 256, 0, stream>>>(h1part, gnn_b1, gnn_w2, gnn_b2,
                                       fin_w, cm, top_idx, Mm);
    k_out<<<64, 128, 0, stream>>>(Mm, fin_b, dropped, out);
}

// Round 6
// 597.843 us; speedup vs baseline: 1.3539x; 1.3539x over previous
//
#include <hip/hip_runtime.h>

// YOLO_GNN on MI355X — round 6: un-fused conv (conv1 NCHW -> LDS-staged
// conv2gap, no overfetch) + 512-thread expert2.
// prep -> conv1 -> conv2gap -> mid -> h1part(x8) -> expert2 -> out.

typedef float f32x4 __attribute__((ext_vector_type(4)));

// ---------------- prep: zero pooled; transpose conv weights ----------------
__global__ void k_prep(const float* __restrict__ w1, const float* __restrict__ w2,
                       float* __restrict__ wt1, float* __restrict__ wt2,
                       float* __restrict__ pooled) {
    int i = blockIdx.x * 256 + threadIdx.x;
    if (i < 4096) pooled[i] = 0.f;
    if (i < 864) {            // conv1: 32 co x 27 k -> [k][co]
        int k = i >> 5, co = i & 31;
        wt1[i] = w1[co * 27 + k];
    }
    if (i < 18432) {          // conv2: ((ky*32+ci)*3+kx)*64+co
        int co = i & 63, tt = i >> 6;
        int kx = tt % 3, u = tt / 3;
        int ci = u & 31, ky = u >> 5;
        wt2[i] = w2[co * 288 + ci * 9 + ky * 3 + kx];
    }
}

// ---------------- conv1: 3->32, stride 2, SAME (pad hi only), ReLU, NCHW out --------------
__global__ __launch_bounds__(256) void k_conv1(const float* __restrict__ x,
                                               const float* __restrict__ wt1,
                                               const float* __restrict__ bias,
                                               float* __restrict__ out) {
    int gid = blockIdx.x * 256 + threadIdx.x;       // 64*112*112 = 802816 exactly
    int ox = gid % 112;
    int t = gid / 112;
    int oy = t % 112;
    int b = t / 112;
    float acc[32];
#pragma unroll
    for (int i = 0; i < 32; i++) acc[i] = 0.f;
    const float* xb = x + (size_t)b * 3 * 224 * 224;
#pragma unroll
    for (int ky = 0; ky < 3; ky++) {
        int iy = 2 * oy + ky;
#pragma unroll
        for (int kx = 0; kx < 3; kx++) {
            int ix = 2 * ox + kx;
            bool ok = (iy < 224) && (ix < 224);     // pad_lo=0, pad_hi=1
#pragma unroll
            for (int ci = 0; ci < 3; ci++) {
                float v = ok ? xb[((size_t)ci * 224 + iy) * 224 + ix] : 0.f;
                const float* w = wt1 + ((ci * 3 + ky) * 3 + kx) * 32;  // uniform -> s_load
#pragma unroll
                for (int co = 0; co < 32; co++) acc[co] = fmaf(v, w[co], acc[co]);
            }
        }
    }
    float* ob = out + (size_t)b * 32 * 12544 + oy * 112 + ox;
#pragma unroll
    for (int co = 0; co < 32; co++) {
        float r = acc[co] + bias[co];
        ob[(size_t)co * 12544] = r > 0.f ? r : 0.f;
    }
}

// ---------------- conv2 (32->64, s2) + ReLU + GAP, LDS-staged input ----------------
// Block = one conv2 output row (oy) of image b; 256 threads = 4 waves.
// Stage s[ci][r][116]: rows iy=2oy..2oy+2 of all 32 channels, float4 copies.
__global__ __launch_bounds__(256) void k_conv2gap(const float* __restrict__ h1,
                                                  const float* __restrict__ wt2,
                                                  const float* __restrict__ b2,
                                                  float* __restrict__ pooled) {
    __shared__ float s[32][3][116];     // 44544 B; row stride 464B (16B-aligned)
    int oy = blockIdx.x;                // 0..55
    int b = blockIdx.y;                 // 0..63
    int tid = threadIdx.x;

    if (tid < 96) {                     // zero pad cols 112..115
        int ci = tid / 3, r = tid - ci * 3;
        *(float4*)&s[ci][r][112] = make_float4(0.f, 0.f, 0.f, 0.f);
    }
    // main copy: 96 rows x 28 float4, coalesced
    for (int i = tid; i < 2688; i += 256) {
        int row = i / 28, f4 = i - row * 28;
        int ci = row / 3, r = row - ci * 3;
        int iy = 2 * oy + r;
        float4 v = make_float4(0.f, 0.f, 0.f, 0.f);
        if (iy < 112)
            v = *(const float4*)&h1[(((size_t)b * 32 + ci) * 112 + iy) * 112 + 4 * f4];
        *(float4*)&s[ci][r][4 * f4] = v;
    }
    __syncthreads();

    // conv2: wave q -> co [16q,16q+16); lane -> opx
    int q = __builtin_amdgcn_readfirstlane((int)(tid >> 6));
    int lane = tid & 63;
    bool pvld = lane < 56;
    int opx = pvld ? lane : 55;
    float acc[16];
#pragma unroll
    for (int j = 0; j < 16; j++) acc[j] = 0.f;
#pragma unroll
    for (int ky = 0; ky < 3; ky++) {
#pragma unroll 4
        for (int ci = 0; ci < 32; ci++) {
            float2 v01 = *(const float2*)&s[ci][ky][2 * opx];    // kx=0,1
            float v2 = s[ci][ky][2 * opx + 2];                   // kx=2
            const float* w = wt2 + ((ky * 32 + ci) * 3) * 64 + q * 16;  // uniform -> s_load
#pragma unroll
            for (int j = 0; j < 16; j++) acc[j] = fmaf(v01.x, w[j], acc[j]);
#pragma unroll
            for (int j = 0; j < 16; j++) acc[j] = fmaf(v01.y, w[64 + j], acc[j]);
#pragma unroll
            for (int j = 0; j < 16; j++) acc[j] = fmaf(v2, w[128 + j], acc[j]);
        }
    }
#pragma unroll
    for (int j = 0; j < 16; j++) {
        float rv = pvld ? fmaxf(acc[j] + b2[q * 16 + j], 0.f) : 0.f;
#pragma unroll
        for (int sft = 32; sft > 0; sft >>= 1) rv += __shfl_xor(rv, sft);
        if (lane == 0) atomicAdd(&pooled[b * 64 + q * 16 + j], rv);
    }
}

// ---------------- mid: feats -> logits -> top2 -> graph(cm,dropped) -> agg ----------------
__global__ __launch_bounds__(256) void k_mid(const float* __restrict__ pooled,
                                             const float* __restrict__ fcf_w,
                                             const float* __restrict__ fcf_b,
                                             const float* __restrict__ fcc_w,
                                             const float* __restrict__ fcc_b,
                                             int* __restrict__ top_idx,
                                             float* __restrict__ cm,
                                             int* __restrict__ dropped,
                                             float* __restrict__ agg) {
    __shared__ float sf[1024];
    __shared__ float slog[2][80];
    __shared__ float sr[10][4];
    __shared__ float sAn[25];
    int b = blockIdx.x, t = threadIdx.x;

    {   // feats = relu(pooled/3136 @ fcf_w + fcf_b)
        float acc[4];
#pragma unroll
        for (int j = 0; j < 4; j++) acc[j] = fcf_b[t + j * 256];
        for (int cc = 0; cc < 64; cc++) {
            float pv = pooled[b * 64 + cc] * (1.f / 3136.f);    // uniform
#pragma unroll
            for (int j = 0; j < 4; j++)
                acc[j] = fmaf(pv, fcf_w[cc * 1024 + t + j * 256], acc[j]);
        }
#pragma unroll
        for (int j = 0; j < 4; j++) sf[t + j * 256] = fmaxf(acc[j], 0.f);
    }
    __syncthreads();

    if (t < 160) {      // logits halves: c=t%80, half=t/80 over 512 f each
        int c = t % 80, half = t / 80;
        float acc = half ? 0.f : fcc_b[c];
        for (int f = half * 512; f < half * 512 + 512; f++)
            acc = fmaf(sf[f], fcc_w[f * 80 + c], acc);
        slog[half][c] = acc;
    }
    {   // graph quarter norms/dots
        float q1 = sf[t], q2 = sf[256 + t], q3 = sf[512 + t], q4 = sf[768 + t];
        float part[10] = {q1 * q1, q2 * q2, q3 * q3, q4 * q4,
                          q1 * q2, q1 * q3, q1 * q4, q2 * q3, q2 * q4, q3 * q4};
        int lane = t & 63, wid = t >> 6;
#pragma unroll
        for (int i = 0; i < 10; i++) {
            float r = part[i];
#pragma unroll
            for (int sft = 32; sft > 0; sft >>= 1) r += __shfl_xor(r, sft);
            if (lane == 0) sr[i][wid] = r;
        }
    }
    __syncthreads();

    if (t < 64) {       // top2 via wave butterfly (tie: lower index)
        int ln = t;
        float vA = slog[0][ln] + slog[1][ln];
        int iA = ln;
        bool hasB = ln < 16;
        float vB = hasB ? slog[0][64 + ln] + slog[1][64 + ln] : -3.4e38f;
        int iB = hasB ? 64 + ln : 0x7fffffff;
        float v1, v2; int i1, i2;
        if (vB > vA) { v1 = vB; i1 = iB; v2 = vA; i2 = iA; }
        else         { v1 = vA; i1 = iA; v2 = vB; i2 = iB; }
#pragma unroll
        for (int m = 1; m < 64; m <<= 1) {
            float o1 = __shfl_xor(v1, m), o2 = __shfl_xor(v2, m);
            int oi1 = __shfl_xor(i1, m), oi2 = __shfl_xor(i2, m);
            bool selfWins = (v1 > o1) || (v1 == o1 && i1 < oi1);
            float n1, n2; int ni1, ni2;
            if (selfWins) {
                n1 = v1; ni1 = i1;
                bool s2 = (v2 > o1) || (v2 == o1 && i2 < oi1);
                n2 = s2 ? v2 : o1; ni2 = s2 ? i2 : oi1;
            } else {
                n1 = o1; ni1 = oi1;
                bool s2 = (v1 > o2) || (v1 == o2 && i1 < oi2);
                n2 = s2 ? v1 : o2; ni2 = s2 ? i1 : oi2;
            }
            v1 = n1; i1 = ni1; v2 = n2; i2 = ni2;
        }
        if (ln == 0) { top_idx[b * 2] = i1; top_idx[b * 2 + 1] = i2; }
    }
    if (t == 0) {       // graph: d2 -> knn -> An(LDS), cm, dropped
        float tot[10];
#pragma unroll
        for (int i = 0; i < 10; i++) tot[i] = sr[i][0] + sr[i][1] + sr[i][2] + sr[i][3];
        float n_[5] = {0.f, tot[0], tot[1], tot[2], tot[3]};
        float dd[5][5];
        dd[1][1] = tot[0]; dd[2][2] = tot[1]; dd[3][3] = tot[2]; dd[4][4] = tot[3];
        dd[1][2] = dd[2][1] = tot[4]; dd[1][3] = dd[3][1] = tot[5];
        dd[1][4] = dd[4][1] = tot[6]; dd[2][3] = dd[3][2] = tot[7];
        dd[2][4] = dd[4][2] = tot[8]; dd[3][4] = dd[4][3] = tot[9];
        float Q = tot[0] + tot[1] + tot[2] + tot[3];
        float d2[5][5];
        d2[0][0] = 0.f;
        for (int i = 1; i < 5; i++) {
            float v = Q + n_[i] - 2.f * dd[1][i];
            d2[0][i] = v; d2[i][0] = v;
        }
        for (int i = 1; i < 5; i++)
            for (int j = 1; j < 5; j++)
                d2[i][j] = (i == j) ? 0.f : (n_[i] + n_[j] - 2.f * dd[i][j]);
        int drp[5];
        for (int r = 0; r < 5; r++) {
            int dm = 0; float vm = d2[r][0];
            for (int ss = 1; ss < 5; ss++)
                if (d2[r][ss] >= vm) { vm = d2[r][ss]; dm = ss; }
            drp[r] = dm;
            dropped[b * 5 + r] = dm;
        }
        float dinv[5], Ah[5][5];
        for (int r = 0; r < 5; r++) {
            float dsum = 0.f;
            for (int ss = 0; ss < 5; ss++) {
                float a = ((ss != drp[r]) ? 1.f : 0.f) + ((ss == r) ? 1.f : 0.f);
                Ah[r][ss] = a; dsum += a;
            }
            dinv[r] = dsum > 0.f ? 1.f / sqrtf(dsum) : 0.f;
        }
        float colsum[5] = {0.f, 0.f, 0.f, 0.f, 0.f};
        for (int r = 0; r < 5; r++)
            for (int ss = 0; ss < 5; ss++) {
                float v = Ah[r][ss] * dinv[r] * dinv[ss];
                sAn[r * 5 + ss] = v;
                colsum[ss] += v;
            }
        for (int ss = 0; ss < 5; ss++) cm[b * 5 + ss] = colsum[ss] * 0.2f;
    }
    __syncthreads();

    // agg = An @ Xg
    for (int f = t; f < 1024; f += 256) {
        float a0 = sf[f];
        bool inq = f < 256;
        float v1 = 0.f, v2 = 0.f, v3 = 0.f, v4 = 0.f;
        if (inq) { v1 = sf[f]; v2 = sf[256 + f]; v3 = sf[512 + f]; v4 = sf[768 + f]; }
#pragma unroll
        for (int tt = 0; tt < 5; tt++) {
            float r = sAn[tt * 5] * a0;
            if (inq)
                r += sAn[tt * 5 + 1] * v1 + sAn[tt * 5 + 2] * v2 +
                     sAn[tt * 5 + 3] * v3 + sAn[tt * 5 + 4] * v4;
            agg[((size_t)b * 5 + tt) * 1024 + f] = r;
        }
    }
}

// ---------------- expert layer1 partials: h1part[fc][pair][t][h] (1024 blocks) ----------------
__global__ __launch_bounds__(128) void k_h1part(const float* __restrict__ agg,
                                                const float* __restrict__ w1,
                                                const int* __restrict__ top_idx,
                                                float* __restrict__ h1part) {
    int pair = blockIdx.x;              // 128
    int fc = blockIdx.y;                // 8 chunks of 128 f
    int hg = threadIdx.x;               // h = 4*hg
    int bsm = pair >> 1;
    int c = top_idx[pair];
    const f32x4* wv = (const f32x4*)(w1 + (size_t)c * 1024 * 512);
    const f32x4* av = (const f32x4*)(agg + (size_t)bsm * 5 * 1024);
    f32x4 acc[5];
#pragma unroll
    for (int t = 0; t < 5; t++) acc[t] = (f32x4)(0.f);
    int f0 = fc * 128;
#pragma unroll 2
    for (int f4 = 0; f4 < 32; f4++) {
        f32x4 a[5];
#pragma unroll
        for (int t = 0; t < 5; t++) a[t] = av[t * 256 + fc * 32 + f4];  // uniform
#pragma unroll
        for (int j = 0; j < 4; j++) {
            f32x4 w = wv[(size_t)(f0 + f4 * 4 + j) * 128 + hg];         // 16B coalesced
#pragma unroll
            for (int t = 0; t < 5; t++) acc[t] += a[t][j] * w;
        }
    }
    float* op = h1part + (((size_t)fc * 128 + pair) * 5) * 512;
#pragma unroll
    for (int t = 0; t < 5; t++)
        *(f32x4*)(op + t * 512 + 4 * hg) = acc[t];
}

// ---------------- expert2: fold + relu/cm + layer2 + b2 + @fin_w (512 thr) ----------------
__global__ __launch_bounds__(512) void k_expert2(const float* __restrict__ h1part,
                                                 const float* __restrict__ b1,
                                                 const float* __restrict__ w2,
                                                 const float* __restrict__ b2,
                                                 const float* __restrict__ finw,
                                                 const float* __restrict__ cm,
                                                 const int* __restrict__ top_idx,
                                                 float* __restrict__ M) {
    __shared__ float sp[512];
    __shared__ float sgq[8][256];
    __shared__ float sgg[256];
    int pair = blockIdx.x, t = threadIdx.x;
    int bsm = pair >> 1;
    int c = top_idx[pair];

    {   // fold: p[h] = sum_t cm[t]*relu(sum_fc part + b1), h = t
        float pv = 0.f;
#pragma unroll
        for (int tt = 0; tt < 5; tt++) {
            float sv = 0.f;
#pragma unroll
            for (int fc = 0; fc < 8; fc++)
                sv += h1part[(((size_t)fc * 128 + pair) * 5 + tt) * 512 + t];
            float hv = fmaxf(sv + b1[c * 512 + t], 0.f);
            pv = fmaf(cm[bsm * 5 + tt], hv, pv);
        }
        sp[t] = pv;
    }
    __syncthreads();

    {   // layer 2: og = t&63 (o-group of 4), hq = t>>6 (h-eighth of 64)
        int og = t & 63, hq = t >> 6;
        const f32x4* wv2 = (const f32x4*)(w2 + (size_t)c * 512 * 256);
        f32x4 acc2 = (f32x4)(0.f);
#pragma unroll 4
        for (int h = hq * 64; h < hq * 64 + 64; h++)
            acc2 += sp[h] * wv2[(size_t)h * 64 + og];            // sp broadcast
        *(f32x4*)&sgq[hq][og * 4] = acc2;
    }
    __syncthreads();
    if (t < 64) {
        f32x4 gsum = *(const f32x4*)&sgq[0][t * 4];
#pragma unroll
        for (int hq = 1; hq < 8; hq++) gsum += *(const f32x4*)&sgq[hq][t * 4];
        gsum += *(const f32x4*)&b2[c * 256 + 4 * t];
        *(f32x4*)&sgg[4 * t] = gsum;
    }
    __syncthreads();
    if (t < 80) {       // M[pair] = g @ fin_w
        float acc3 = 0.f;
        for (int o = 0; o < 256; o++) acc3 = fmaf(sgg[o], finw[o * 80 + t], acc3);
        M[pair * 80 + t] = acc3;
    }
}

// ---------------- final GCN + mean over k ----------------
__global__ __launch_bounds__(128) void k_out(const float* __restrict__ M,
                                             const float* __restrict__ finb,
                                             const int* __restrict__ dropped,
                                             float* __restrict__ out) {
    int b = blockIdx.x;
    int c = threadIdx.x;
    if (c >= 80) return;
    float bias = finb[c];
    float r = 0.f;
#pragma unroll
    for (int k = 0; k < 2; k++) {
        int n = b * 2 + k;
        float fin;
        if (n < 5) {
            float s = 0.f;
            for (int m = 0; m < 5; m++) {
                float a = ((m != dropped[63 * 5 + n]) ? 1.f : 0.f) + ((m == n) ? 1.f : 0.f);
                s += a * M[m * 80 + c];
            }
            fin = s * 0.2f + bias;
        } else {
            fin = M[n * 80 + c] + bias;
        }
        r += fin;
    }
    out[b * 80 + c] = r * 0.5f;
}

extern "C" void kernel_launch(void* const* d_in, const int* in_sizes, int n_in,
                              void* d_out, int out_size, void* d_ws, size_t ws_size,
                              hipStream_t stream) {
    const float* x       = (const float*)d_in[0];
    const float* conv1_w = (const float*)d_in[1];
    const float* conv1_b = (const float*)d_in[2];
    const float* conv2_w = (const float*)d_in[3];
    const float* conv2_b = (const float*)d_in[4];
    const float* fcf_w   = (const float*)d_in[5];
    const float* fcf_b   = (const float*)d_in[6];
    const float* fcc_w   = (const float*)d_in[7];
    const float* fcc_b   = (const float*)d_in[8];
    const float* gnn_w1  = (const float*)d_in[9];
    const float* gnn_b1  = (const float*)d_in[10];
    const float* gnn_w2  = (const float*)d_in[11];
    const float* gnn_b2  = (const float*)d_in[12];
    const float* fin_w   = (const float*)d_in[13];
    const float* fin_b   = (const float*)d_in[14];
    float* out = (float*)d_out;

    char* ws = (char*)d_ws;
    size_t off = 0;
    auto alloc = [&](size_t bytes) {
        void* pp = ws + off;
        off = (off + bytes + 255) & ~(size_t)255;
        return pp;
    };
    float* h1conv  = (float*)alloc((size_t)64 * 32 * 112 * 112 * 4);  // 102.8 MB
    float* wt1     = (float*)alloc(864 * 4);
    float* wt2     = (float*)alloc(18432 * 4);
    float* pooled  = (float*)alloc(4096 * 4);
    int*   top_idx = (int*)alloc(128 * 4);
    float* cm      = (float*)alloc(320 * 4);
    int*   dropped = (int*)alloc(320 * 4);
    float* agg     = (float*)alloc(327680 * 4);
    float* h1part  = (float*)alloc((size_t)2621440 * 4);   // 8*128*5*512 = 10.5 MB
    float* Mm      = (float*)alloc(10240 * 4);
    (void)ws_size; (void)in_sizes; (void)n_in; (void)out_size;

    k_prep<<<72, 256, 0, stream>>>(conv1_w, conv2_w, wt1, wt2, pooled);
    k_conv1<<<3136, 256, 0, stream>>>(x, wt1, conv1_b, h1conv);
    k_conv2gap<<<dim3(56, 64), 256, 0, stream>>>(h1conv, wt2, conv2_b, pooled);
    k_mid<<<64, 256, 0, stream>>>(pooled, fcf_w, fcf_b, fcc_w, fcc_b,
                                  top_idx, cm, dropped, agg);
    k_h1part<<<dim3(128, 8), 128, 0, stream>>>(agg, gnn_w1, top_idx, h1part);
    k_expert2<<<128, 512, 0, stream>>>(h1part, gnn_b1, gnn_w2, gnn_b2,
                                       fin_w, cm, top_idx, Mm);
    k_out<<<64, 128, 0, stream>>>(Mm, fin_b, dropped, out);
}

// Round 7
// 543.660 us; speedup vs baseline: 1.4888x; 1.0997x over previous
//
#include <hip/hip_runtime.h>

// YOLO_GNN on MI355X — round 7: conv2gap computes 2 output rows per block
// (2x FLOPs per scalar weight load — attacks the s_load stall that capped
// VALUBusy at 33%). Tail unchanged.
// prep -> conv1 -> conv2gap -> mid -> h1part(x8) -> expert2 -> out.

typedef float f32x4 __attribute__((ext_vector_type(4)));

// ---------------- prep: zero pooled; transpose conv weights ----------------
__global__ void k_prep(const float* __restrict__ w1, const float* __restrict__ w2,
                       float* __restrict__ wt1, float* __restrict__ wt2,
                       float* __restrict__ pooled) {
    int i = blockIdx.x * 256 + threadIdx.x;
    if (i < 4096) pooled[i] = 0.f;
    if (i < 864) {            // conv1: 32 co x 27 k -> [k][co]
        int k = i >> 5, co = i & 31;
        wt1[i] = w1[co * 27 + k];
    }
    if (i < 18432) {          // conv2: ((ky*32+ci)*3+kx)*64+co
        int co = i & 63, tt = i >> 6;
        int kx = tt % 3, u = tt / 3;
        int ci = u & 31, ky = u >> 5;
        wt2[i] = w2[co * 288 + ci * 9 + ky * 3 + kx];
    }
}

// ---------------- conv1: 3->32, stride 2, SAME (pad hi only), ReLU, NCHW out --------------
__global__ __launch_bounds__(256) void k_conv1(const float* __restrict__ x,
                                               const float* __restrict__ wt1,
                                               const float* __restrict__ bias,
                                               float* __restrict__ out) {
    int gid = blockIdx.x * 256 + threadIdx.x;       // 64*112*112 = 802816 exactly
    int ox = gid % 112;
    int t = gid / 112;
    int oy = t % 112;
    int b = t / 112;
    float acc[32];
#pragma unroll
    for (int i = 0; i < 32; i++) acc[i] = 0.f;
    const float* xb = x + (size_t)b * 3 * 224 * 224;
#pragma unroll
    for (int ky = 0; ky < 3; ky++) {
        int iy = 2 * oy + ky;
#pragma unroll
        for (int kx = 0; kx < 3; kx++) {
            int ix = 2 * ox + kx;
            bool ok = (iy < 224) && (ix < 224);     // pad_lo=0, pad_hi=1
#pragma unroll
            for (int ci = 0; ci < 3; ci++) {
                float v = ok ? xb[((size_t)ci * 224 + iy) * 224 + ix] : 0.f;
                const float* w = wt1 + ((ci * 3 + ky) * 3 + kx) * 32;  // uniform -> s_load
#pragma unroll
                for (int co = 0; co < 32; co++) acc[co] = fmaf(v, w[co], acc[co]);
            }
        }
    }
    float* ob = out + (size_t)b * 32 * 12544 + oy * 112 + ox;
#pragma unroll
    for (int co = 0; co < 32; co++) {
        float r = acc[co] + bias[co];
        ob[(size_t)co * 12544] = r > 0.f ? r : 0.f;
    }
}

// ---------------- conv2 (32->64, s2) + ReLU + GAP, 2 output rows per block ----------------
// Block = (oy pair, image b); 256 threads = 4 waves. Stage 5 conv1 rows
// (iy = 4*oy2 .. 4*oy2+4, halo shared between the 2 outputs) as float4 copies.
// Wave q -> co [16q,16q+16); lane -> opx; 2 rows x 16 co accumulators: each
// scalar-loaded weight feeds 32 FMAs (vs 16 in round 6) -> s_load stall halves.
__global__ __launch_bounds__(256) void k_conv2gap(const float* __restrict__ h1,
                                                  const float* __restrict__ wt2,
                                                  const float* __restrict__ b2,
                                                  float* __restrict__ pooled) {
    __shared__ float s[32][5][116];     // 74240 B -> 2 blocks/CU
    int oy2 = blockIdx.x;               // 0..27 -> oy = 2*oy2 + ry
    int b = blockIdx.y;                 // 0..63
    int tid = threadIdx.x;

    // stage: 160 lds-rows (ci*5+r) x 29 float4
    for (int i = tid; i < 4640; i += 256) {
        int row = i / 29, f4 = i - row * 29;
        int ci = row / 5, r = row - ci * 5;
        int iy = 4 * oy2 + r;
        float4 v = make_float4(0.f, 0.f, 0.f, 0.f);
        if (f4 < 28 && iy < 112)
            v = *(const float4*)&h1[(((size_t)b * 32 + ci) * 112 + iy) * 112 + 4 * f4];
        *(float4*)&s[ci][r][4 * f4] = v;
    }
    __syncthreads();

    int q = __builtin_amdgcn_readfirstlane((int)(tid >> 6));
    int lane = tid & 63;
    bool pvld = lane < 56;
    int opx = pvld ? lane : 55;
    float acc[2][16];
#pragma unroll
    for (int ry = 0; ry < 2; ry++)
#pragma unroll
        for (int j = 0; j < 16; j++) acc[ry][j] = 0.f;

#pragma unroll
    for (int ky = 0; ky < 3; ky++) {
#pragma unroll 4
        for (int ci = 0; ci < 32; ci++) {
            const float* w = wt2 + ((ky * 32 + ci) * 3) * 64 + q * 16;  // uniform -> s_load
#pragma unroll
            for (int ry = 0; ry < 2; ry++) {
                int r = 2 * ry + ky;                                    // input row
                float2 v01 = *(const float2*)&s[ci][r][2 * opx];        // kx=0,1
                float v2 = s[ci][r][2 * opx + 2];                       // kx=2
#pragma unroll
                for (int j = 0; j < 16; j++) acc[ry][j] = fmaf(v01.x, w[j], acc[ry][j]);
#pragma unroll
                for (int j = 0; j < 16; j++) acc[ry][j] = fmaf(v01.y, w[64 + j], acc[ry][j]);
#pragma unroll
                for (int j = 0; j < 16; j++) acc[ry][j] = fmaf(v2, w[128 + j], acc[ry][j]);
            }
        }
    }
    // bias+relu per (row, px), sum rows, reduce across lanes, 1 atomic per co
#pragma unroll
    for (int j = 0; j < 16; j++) {
        float bj = b2[q * 16 + j];
        float rv = 0.f;
        if (pvld)
            rv = fmaxf(acc[0][j] + bj, 0.f) + fmaxf(acc[1][j] + bj, 0.f);
#pragma unroll
        for (int sft = 32; sft > 0; sft >>= 1) rv += __shfl_xor(rv, sft);
        if (lane == 0) atomicAdd(&pooled[b * 64 + q * 16 + j], rv);
    }
}

// ---------------- mid: feats -> logits -> top2 -> graph(cm,dropped) -> agg ----------------
__global__ __launch_bounds__(256) void k_mid(const float* __restrict__ pooled,
                                             const float* __restrict__ fcf_w,
                                             const float* __restrict__ fcf_b,
                                             const float* __restrict__ fcc_w,
                                             const float* __restrict__ fcc_b,
                                             int* __restrict__ top_idx,
                                             float* __restrict__ cm,
                                             int* __restrict__ dropped,
                                             float* __restrict__ agg) {
    __shared__ float sf[1024];
    __shared__ float slog[2][80];
    __shared__ float sr[10][4];
    __shared__ float sAn[25];
    int b = blockIdx.x, t = threadIdx.x;

    {   // feats = relu(pooled/3136 @ fcf_w + fcf_b)
        float acc[4];
#pragma unroll
        for (int j = 0; j < 4; j++) acc[j] = fcf_b[t + j * 256];
        for (int cc = 0; cc < 64; cc++) {
            float pv = pooled[b * 64 + cc] * (1.f / 3136.f);    // uniform
#pragma unroll
            for (int j = 0; j < 4; j++)
                acc[j] = fmaf(pv, fcf_w[cc * 1024 + t + j * 256], acc[j]);
        }
#pragma unroll
        for (int j = 0; j < 4; j++) sf[t + j * 256] = fmaxf(acc[j], 0.f);
    }
    __syncthreads();

    if (t < 160) {      // logits halves: c=t%80, half=t/80 over 512 f each
        int c = t % 80, half = t / 80;
        float acc = half ? 0.f : fcc_b[c];
        for (int f = half * 512; f < half * 512 + 512; f++)
            acc = fmaf(sf[f], fcc_w[f * 80 + c], acc);
        slog[half][c] = acc;
    }
    {   // graph quarter norms/dots
        float q1 = sf[t], q2 = sf[256 + t], q3 = sf[512 + t], q4 = sf[768 + t];
        float part[10] = {q1 * q1, q2 * q2, q3 * q3, q4 * q4,
                          q1 * q2, q1 * q3, q1 * q4, q2 * q3, q2 * q4, q3 * q4};
        int lane = t & 63, wid = t >> 6;
#pragma unroll
        for (int i = 0; i < 10; i++) {
            float r = part[i];
#pragma unroll
            for (int sft = 32; sft > 0; sft >>= 1) r += __shfl_xor(r, sft);
            if (lane == 0) sr[i][wid] = r;
        }
    }
    __syncthreads();

    if (t < 64) {       // top2 via wave butterfly (tie: lower index)
        int ln = t;
        float vA = slog[0][ln] + slog[1][ln];
        int iA = ln;
        bool hasB = ln < 16;
        float vB = hasB ? slog[0][64 + ln] + slog[1][64 + ln] : -3.4e38f;
        int iB = hasB ? 64 + ln : 0x7fffffff;
        float v1, v2; int i1, i2;
        if (vB > vA) { v1 = vB; i1 = iB; v2 = vA; i2 = iA; }
        else         { v1 = vA; i1 = iA; v2 = vB; i2 = iB; }
#pragma unroll
        for (int m = 1; m < 64; m <<= 1) {
            float o1 = __shfl_xor(v1, m), o2 = __shfl_xor(v2, m);
            int oi1 = __shfl_xor(i1, m), oi2 = __shfl_xor(i2, m);
            bool selfWins = (v1 > o1) || (v1 == o1 && i1 < oi1);
            float n1, n2; int ni1, ni2;
            if (selfWins) {
                n1 = v1; ni1 = i1;
                bool s2 = (v2 > o1) || (v2 == o1 && i2 < oi1);
                n2 = s2 ? v2 : o1; ni2 = s2 ? i2 : oi1;
            } else {
                n1 = o1; ni1 = oi1;
                bool s2 = (v1 > o2) || (v1 == o2 && i1 < oi2);
                n2 = s2 ? v1 : o2; ni2 = s2 ? i1 : oi2;
            }
            v1 = n1; i1 = ni1; v2 = n2; i2 = ni2;
        }
        if (ln == 0) { top_idx[b * 2] = i1; top_idx[b * 2 + 1] = i2; }
    }
    if (t == 0) {       // graph: d2 -> knn -> An(LDS), cm, dropped
        float tot[10];
#pragma unroll
        for (int i = 0; i < 10; i++) tot[i] = sr[i][0] + sr[i][1] + sr[i][2] + sr[i][3];
        float n_[5] = {0.f, tot[0], tot[1], tot[2], tot[3]};
        float dd[5][5];
        dd[1][1] = tot[0]; dd[2][2] = tot[1]; dd[3][3] = tot[2]; dd[4][4] = tot[3];
        dd[1][2] = dd[2][1] = tot[4]; dd[1][3] = dd[3][1] = tot[5];
        dd[1][4] = dd[4][1] = tot[6]; dd[2][3] = dd[3][2] = tot[7];
        dd[2][4] = dd[4][2] = tot[8]; dd[3][4] = dd[4][3] = tot[9];
        float Q = tot[0] + tot[1] + tot[2] + tot[3];
        float d2[5][5];
        d2[0][0] = 0.f;
        for (int i = 1; i < 5; i++) {
            float v = Q + n_[i] - 2.f * dd[1][i];
            d2[0][i] = v; d2[i][0] = v;
        }
        for (int i = 1; i < 5; i++)
            for (int j = 1; j < 5; j++)
                d2[i][j] = (i == j) ? 0.f : (n_[i] + n_[j] - 2.f * dd[i][j]);
        int drp[5];
        for (int r = 0; r < 5; r++) {
            int dm = 0; float vm = d2[r][0];
            for (int ss = 1; ss < 5; ss++)
                if (d2[r][ss] >= vm) { vm = d2[r][ss]; dm = ss; }
            drp[r] = dm;
            dropped[b * 5 + r] = dm;
        }
        float dinv[5], Ah[5][5];
        for (int r = 0; r < 5; r++) {
            float dsum = 0.f;
            for (int ss = 0; ss < 5; ss++) {
                float a = ((ss != drp[r]) ? 1.f : 0.f) + ((ss == r) ? 1.f : 0.f);
                Ah[r][ss] = a; dsum += a;
            }
            dinv[r] = dsum > 0.f ? 1.f / sqrtf(dsum) : 0.f;
        }
        float colsum[5] = {0.f, 0.f, 0.f, 0.f, 0.f};
        for (int r = 0; r < 5; r++)
            for (int ss = 0; ss < 5; ss++) {
                float v = Ah[r][ss] * dinv[r] * dinv[ss];
                sAn[r * 5 + ss] = v;
                colsum[ss] += v;
            }
        for (int ss = 0; ss < 5; ss++) cm[b * 5 + ss] = colsum[ss] * 0.2f;
    }
    __syncthreads();

    // agg = An @ Xg
    for (int f = t; f < 1024; f += 256) {
        float a0 = sf[f];
        bool inq = f < 256;
        float v1 = 0.f, v2 = 0.f, v3 = 0.f, v4 = 0.f;
        if (inq) { v1 = sf[f]; v2 = sf[256 + f]; v3 = sf[512 + f]; v4 = sf[768 + f]; }
#pragma unroll
        for (int tt = 0; tt < 5; tt++) {
            float r = sAn[tt * 5] * a0;
            if (inq)
                r += sAn[tt * 5 + 1] * v1 + sAn[tt * 5 + 2] * v2 +
                     sAn[tt * 5 + 3] * v3 + sAn[tt * 5 + 4] * v4;
            agg[((size_t)b * 5 + tt) * 1024 + f] = r;
        }
    }
}

// ---------------- expert layer1 partials: h1part[fc][pair][t][h] (1024 blocks) ----------------
__global__ __launch_bounds__(128) void k_h1part(const float* __restrict__ agg,
                                                const float* __restrict__ w1,
                                                const int* __restrict__ top_idx,
                                                float* __restrict__ h1part) {
    int pair = blockIdx.x;              // 128
    int fc = blockIdx.y;                // 8 chunks of 128 f
    int hg = threadIdx.x;               // h = 4*hg
    int bsm = pair >> 1;
    int c = top_idx[pair];
    const f32x4* wv = (const f32x4*)(w1 + (size_t)c * 1024 * 512);
    const f32x4* av = (const f32x4*)(agg + (size_t)bsm * 5 * 1024);
    f32x4 acc[5];
#pragma unroll
    for (int t = 0; t < 5; t++) acc[t] = (f32x4)(0.f);
    int f0 = fc * 128;
#pragma unroll 2
    for (int f4 = 0; f4 < 32; f4++) {
        f32x4 a[5];
#pragma unroll
        for (int t = 0; t < 5; t++) a[t] = av[t * 256 + fc * 32 + f4];  // uniform
#pragma unroll
        for (int j = 0; j < 4; j++) {
            f32x4 w = wv[(size_t)(f0 + f4 * 4 + j) * 128 + hg];         // 16B coalesced
#pragma unroll
            for (int t = 0; t < 5; t++) acc[t] += a[t][j] * w;
        }
    }
    float* op = h1part + (((size_t)fc * 128 + pair) * 5) * 512;
#pragma unroll
    for (int t = 0; t < 5; t++)
        *(f32x4*)(op + t * 512 + 4 * hg) = acc[t];
}

// ---------------- expert2: fold + relu/cm + layer2 + b2 + @fin_w (512 thr) ----------------
__global__ __launch_bounds__(512) void k_expert2(const float* __restrict__ h1part,
                                                 const float* __restrict__ b1,
                                                 const float* __restrict__ w2,
                                                 const float* __restrict__ b2,
                                                 const float* __restrict__ finw,
                                                 const float* __restrict__ cm,
                                                 const int* __restrict__ top_idx,
                                                 float* __restrict__ M) {
    __shared__ float sp[512];
    __shared__ float sgq[8][256];
    __shared__ float sgg[256];
    int pair = blockIdx.x, t = threadIdx.x;
    int bsm = pair >> 1;
    int c = top_idx[pair];

    {   // fold: p[h] = sum_t cm[t]*relu(sum_fc part + b1), h = t
        float pv = 0.f;
#pragma unroll
        for (int tt = 0; tt < 5; tt++) {
            float sv = 0.f;
#pragma unroll
            for (int fc = 0; fc < 8; fc++)
                sv += h1part[(((size_t)fc * 128 + pair) * 5 + tt) * 512 + t];
            float hv = fmaxf(sv + b1[c * 512 + t], 0.f);
            pv = fmaf(cm[bsm * 5 + tt], hv, pv);
        }
        sp[t] = pv;
    }
    __syncthreads();

    {   // layer 2: og = t&63 (o-group of 4), hq = t>>6 (h-eighth of 64)
        int og = t & 63, hq = t >> 6;
        const f32x4* wv2 = (const f32x4*)(w2 + (size_t)c * 512 * 256);
        f32x4 acc2 = (f32x4)(0.f);
#pragma unroll 4
        for (int h = hq * 64; h < hq * 64 + 64; h++)
            acc2 += sp[h] * wv2[(size_t)h * 64 + og];            // sp broadcast
        *(f32x4*)&sgq[hq][og * 4] = acc2;
    }
    __syncthreads();
    if (t < 64) {
        f32x4 gsum = *(const f32x4*)&sgq[0][t * 4];
#pragma unroll
        for (int hq = 1; hq < 8; hq++) gsum += *(const f32x4*)&sgq[hq][t * 4];
        gsum += *(const f32x4*)&b2[c * 256 + 4 * t];
        *(f32x4*)&sgg[4 * t] = gsum;
    }
    __syncthreads();
    if (t < 80) {       // M[pair] = g @ fin_w
        float acc3 = 0.f;
        for (int o = 0; o < 256; o++) acc3 = fmaf(sgg[o], finw[o * 80 + t], acc3);
        M[pair * 80 + t] = acc3;
    }
}

// ---------------- final GCN + mean over k ----------------
__global__ __launch_bounds__(128) void k_out(const float* __restrict__ M,
                                             const float* __restrict__ finb,
                                             const int* __restrict__ dropped,
                                             float* __restrict__ out) {
    int b = blockIdx.x;
    int c = threadIdx.x;
    if (c >= 80) return;
    float bias = finb[c];
    float r = 0.f;
#pragma unroll
    for (int k = 0; k < 2; k++) {
        int n = b * 2 + k;
        float fin;
        if (n < 5) {
            float s = 0.f;
            for (int m = 0; m < 5; m++) {
                float a = ((m != dropped[63 * 5 + n]) ? 1.f : 0.f) + ((m == n) ? 1.f : 0.f);
                s += a * M[m * 80 + c];
            }
            fin = s * 0.2f + bias;
        } else {
            fin = M[n * 80 + c] + bias;
        }
        r += fin;
    }
    out[b * 80 + c] = r * 0.5f;
}

extern "C" void kernel_launch(void* const* d_in, const int* in_sizes, int n_in,
                              void* d_out, int out_size, void* d_ws, size_t ws_size,
                              hipStream_t stream) {
    const float* x       = (const float*)d_in[0];
    const float* conv1_w = (const float*)d_in[1];
    const float* conv1_b = (const float*)d_in[2];
    const float* conv2_w = (const float*)d_in[3];
    const float* conv2_b = (const float*)d_in[4];
    const float* fcf_w   = (const float*)d_in[5];
    const float* fcf_b   = (const float*)d_in[6];
    const float* fcc_w   = (const float*)d_in[7];
    const float* fcc_b   = (const float*)d_in[8];
    const float* gnn_w1  = (const float*)d_in[9];
    const float* gnn_b1  = (const float*)d_in[10];
    const float* gnn_w2  = (const float*)d_in[11];
    const float* gnn_b2  = (const float*)d_in[12];
    const float* fin_w   = (const float*)d_in[13];
    const float* fin_b   = (const float*)d_in[14];
    float* out = (float*)d_out;

    char* ws = (char*)d_ws;
    size_t off = 0;
    auto alloc = [&](size_t bytes) {
        void* pp = ws + off;
        off = (off + bytes + 255) & ~(size_t)255;
        return pp;
    };
    float* h1conv  = (float*)alloc((size_t)64 * 32 * 112 * 112 * 4);  // 102.8 MB
    float* wt1     = (float*)alloc(864 * 4);
    float* wt2     = (float*)alloc(18432 * 4);
    float* pooled  = (float*)alloc(4096 * 4);
    int*   top_idx = (int*)alloc(128 * 4);
    float* cm      = (float*)alloc(320 * 4);
    int*   dropped = (int*)alloc(320 * 4);
    float* agg     = (float*)alloc(327680 * 4);
    float* h1part  = (float*)alloc((size_t)2621440 * 4);   // 8*128*5*512 = 10.5 MB
    float* Mm      = (float*)alloc(10240 * 4);
    (void)ws_size; (void)in_sizes; (void)n_in; (void)out_size;

    k_prep<<<72, 256, 0, stream>>>(conv1_w, conv2_w, wt1, wt2, pooled);
    k_conv1<<<3136, 256, 0, stream>>>(x, wt1, conv1_b, h1conv);
    k_conv2gap<<<dim3(28, 64), 256, 0, stream>>>(h1conv, wt2, conv2_b, pooled);
    k_mid<<<64, 256, 0, stream>>>(pooled, fcf_w, fcf_b, fcc_w, fcc_b,
                                  top_idx, cm, dropped, agg);
    k_h1part<<<dim3(128, 8), 128, 0, stream>>>(agg, gnn_w1, top_idx, h1part);
    k_expert2<<<128, 512, 0, stream>>>(h1part, gnn_b1, gnn_w2, gnn_b2,
                                       fin_w, cm, top_idx, Mm);
    k_out<<<64, 128, 0, stream>>>(Mm, fin_b, dropped, out);
}

// Round 8
// 503.887 us; speedup vs baseline: 1.6063x; 1.0789x over previous
//
#include <hip/hip_runtime.h>

// YOLO_GNN on MI355X — round 8: conv2gap channel-split LDS staging (37 KB ->
// 4 blocks/CU, fixes the 2-wave/SIMD occupancy cap of round 7). Tail unchanged
// (conv2gap at ~105 us will force the hidden-slow tail kernel into top-5).
// prep -> conv1 -> conv2gap -> mid -> h1part(x8) -> expert2 -> out.

typedef float f32x4 __attribute__((ext_vector_type(4)));

// ---------------- prep: zero pooled; transpose conv weights ----------------
__global__ void k_prep(const float* __restrict__ w1, const float* __restrict__ w2,
                       float* __restrict__ wt1, float* __restrict__ wt2,
                       float* __restrict__ pooled) {
    int i = blockIdx.x * 256 + threadIdx.x;
    if (i < 4096) pooled[i] = 0.f;
    if (i < 864) {            // conv1: 32 co x 27 k -> [k][co]
        int k = i >> 5, co = i & 31;
        wt1[i] = w1[co * 27 + k];
    }
    if (i < 18432) {          // conv2: ((ky*32+ci)*3+kx)*64+co
        int co = i & 63, tt = i >> 6;
        int kx = tt % 3, u = tt / 3;
        int ci = u & 31, ky = u >> 5;
        wt2[i] = w2[co * 288 + ci * 9 + ky * 3 + kx];
    }
}

// ---------------- conv1: 3->32, stride 2, SAME (pad hi only), ReLU, NCHW out --------------
__global__ __launch_bounds__(256) void k_conv1(const float* __restrict__ x,
                                               const float* __restrict__ wt1,
                                               const float* __restrict__ bias,
                                               float* __restrict__ out) {
    int gid = blockIdx.x * 256 + threadIdx.x;       // 64*112*112 = 802816 exactly
    int ox = gid % 112;
    int t = gid / 112;
    int oy = t % 112;
    int b = t / 112;
    float acc[32];
#pragma unroll
    for (int i = 0; i < 32; i++) acc[i] = 0.f;
    const float* xb = x + (size_t)b * 3 * 224 * 224;
#pragma unroll
    for (int ky = 0; ky < 3; ky++) {
        int iy = 2 * oy + ky;
#pragma unroll
        for (int kx = 0; kx < 3; kx++) {
            int ix = 2 * ox + kx;
            bool ok = (iy < 224) && (ix < 224);     // pad_lo=0, pad_hi=1
#pragma unroll
            for (int ci = 0; ci < 3; ci++) {
                float v = ok ? xb[((size_t)ci * 224 + iy) * 224 + ix] : 0.f;
                const float* w = wt1 + ((ci * 3 + ky) * 3 + kx) * 32;  // uniform -> s_load
#pragma unroll
                for (int co = 0; co < 32; co++) acc[co] = fmaf(v, w[co], acc[co]);
            }
        }
    }
    float* ob = out + (size_t)b * 32 * 12544 + oy * 112 + ox;
#pragma unroll
    for (int co = 0; co < 32; co++) {
        float r = acc[co] + bias[co];
        ob[(size_t)co * 12544] = r > 0.f ? r : 0.f;
    }
}

// ---------------- conv2 (32->64, s2) + ReLU + GAP: 2 rows/block, 16-ch split staging --------
// Block = (oy pair, image b); 256 threads = 4 waves. Two phases; phase cp
// stages channels [16cp,16cp+16), rows iy=4*oy2..4*oy2+4, then accumulates.
// LDS 37120 B -> 4 blocks/CU (16 waves/CU). acc[2][16] carried across phases.
__global__ __launch_bounds__(256) void k_conv2gap(const float* __restrict__ h1,
                                                  const float* __restrict__ wt2,
                                                  const float* __restrict__ b2,
                                                  float* __restrict__ pooled) {
    __shared__ float s[16][5][116];     // 37120 B
    int oy2 = blockIdx.x;               // 0..27
    int b = blockIdx.y;                 // 0..63
    int tid = threadIdx.x;

    int q = __builtin_amdgcn_readfirstlane((int)(tid >> 6));
    int lane = tid & 63;
    bool pvld = lane < 56;
    int opx = pvld ? lane : 55;
    float acc[2][16];
#pragma unroll
    for (int ry = 0; ry < 2; ry++)
#pragma unroll
        for (int j = 0; j < 16; j++) acc[ry][j] = 0.f;

#pragma unroll 1
    for (int cp = 0; cp < 2; cp++) {
        if (cp) __syncthreads();        // all waves done reading s before restage
        // stage 16 channels x 5 rows x 29 float4
        for (int i = tid; i < 2320; i += 256) {
            int row = i / 29, f4 = i - row * 29;
            int ci = row / 5, r = row - ci * 5;
            int iy = 4 * oy2 + r;
            float4 v = make_float4(0.f, 0.f, 0.f, 0.f);
            if (f4 < 28 && iy < 112)
                v = *(const float4*)&h1[(((size_t)b * 32 + cp * 16 + ci) * 112 + iy) * 112 + 4 * f4];
            *(float4*)&s[ci][r][4 * f4] = v;
        }
        __syncthreads();

#pragma unroll
        for (int ky = 0; ky < 3; ky++) {
#pragma unroll 4
            for (int ci = 0; ci < 16; ci++) {
                const float* w = wt2 + ((ky * 32 + cp * 16 + ci) * 3) * 64 + q * 16;  // uniform
#pragma unroll
                for (int ry = 0; ry < 2; ry++) {
                    int r = 2 * ry + ky;                                // input row
                    float2 v01 = *(const float2*)&s[ci][r][2 * opx];    // kx=0,1
                    float v2 = s[ci][r][2 * opx + 2];                   // kx=2
#pragma unroll
                    for (int j = 0; j < 16; j++) acc[ry][j] = fmaf(v01.x, w[j], acc[ry][j]);
#pragma unroll
                    for (int j = 0; j < 16; j++) acc[ry][j] = fmaf(v01.y, w[64 + j], acc[ry][j]);
#pragma unroll
                    for (int j = 0; j < 16; j++) acc[ry][j] = fmaf(v2, w[128 + j], acc[ry][j]);
                }
            }
        }
    }
    // bias+relu per (row, px), sum rows, reduce across lanes, 1 atomic per co
#pragma unroll
    for (int j = 0; j < 16; j++) {
        float bj = b2[q * 16 + j];
        float rv = 0.f;
        if (pvld)
            rv = fmaxf(acc[0][j] + bj, 0.f) + fmaxf(acc[1][j] + bj, 0.f);
#pragma unroll
        for (int sft = 32; sft > 0; sft >>= 1) rv += __shfl_xor(rv, sft);
        if (lane == 0) atomicAdd(&pooled[b * 64 + q * 16 + j], rv);
    }
}

// ---------------- mid: feats -> logits -> top2 -> graph(cm,dropped) -> agg ----------------
__global__ __launch_bounds__(256) void k_mid(const float* __restrict__ pooled,
                                             const float* __restrict__ fcf_w,
                                             const float* __restrict__ fcf_b,
                                             const float* __restrict__ fcc_w,
                                             const float* __restrict__ fcc_b,
                                             int* __restrict__ top_idx,
                                             float* __restrict__ cm,
                                             int* __restrict__ dropped,
                                             float* __restrict__ agg) {
    __shared__ float sf[1024];
    __shared__ float slog[2][80];
    __shared__ float sr[10][4];
    __shared__ float sAn[25];
    int b = blockIdx.x, t = threadIdx.x;

    {   // feats = relu(pooled/3136 @ fcf_w + fcf_b)
        float acc[4];
#pragma unroll
        for (int j = 0; j < 4; j++) acc[j] = fcf_b[t + j * 256];
        for (int cc = 0; cc < 64; cc++) {
            float pv = pooled[b * 64 + cc] * (1.f / 3136.f);    // uniform
#pragma unroll
            for (int j = 0; j < 4; j++)
                acc[j] = fmaf(pv, fcf_w[cc * 1024 + t + j * 256], acc[j]);
        }
#pragma unroll
        for (int j = 0; j < 4; j++) sf[t + j * 256] = fmaxf(acc[j], 0.f);
    }
    __syncthreads();

    if (t < 160) {      // logits halves: c=t%80, half=t/80 over 512 f each
        int c = t % 80, half = t / 80;
        float acc = half ? 0.f : fcc_b[c];
        for (int f = half * 512; f < half * 512 + 512; f++)
            acc = fmaf(sf[f], fcc_w[f * 80 + c], acc);
        slog[half][c] = acc;
    }
    {   // graph quarter norms/dots
        float q1 = sf[t], q2 = sf[256 + t], q3 = sf[512 + t], q4 = sf[768 + t];
        float part[10] = {q1 * q1, q2 * q2, q3 * q3, q4 * q4,
                          q1 * q2, q1 * q3, q1 * q4, q2 * q3, q2 * q4, q3 * q4};
        int lane = t & 63, wid = t >> 6;
#pragma unroll
        for (int i = 0; i < 10; i++) {
            float r = part[i];
#pragma unroll
            for (int sft = 32; sft > 0; sft >>= 1) r += __shfl_xor(r, sft);
            if (lane == 0) sr[i][wid] = r;
        }
    }
    __syncthreads();

    if (t < 64) {       // top2 via wave butterfly (tie: lower index)
        int ln = t;
        float vA = slog[0][ln] + slog[1][ln];
        int iA = ln;
        bool hasB = ln < 16;
        float vB = hasB ? slog[0][64 + ln] + slog[1][64 + ln] : -3.4e38f;
        int iB = hasB ? 64 + ln : 0x7fffffff;
        float v1, v2; int i1, i2;
        if (vB > vA) { v1 = vB; i1 = iB; v2 = vA; i2 = iA; }
        else         { v1 = vA; i1 = iA; v2 = vB; i2 = iB; }
#pragma unroll
        for (int m = 1; m < 64; m <<= 1) {
            float o1 = __shfl_xor(v1, m), o2 = __shfl_xor(v2, m);
            int oi1 = __shfl_xor(i1, m), oi2 = __shfl_xor(i2, m);
            bool selfWins = (v1 > o1) || (v1 == o1 && i1 < oi1);
            float n1, n2; int ni1, ni2;
            if (selfWins) {
                n1 = v1; ni1 = i1;
                bool s2 = (v2 > o1) || (v2 == o1 && i2 < oi1);
                n2 = s2 ? v2 : o1; ni2 = s2 ? i2 : oi1;
            } else {
                n1 = o1; ni1 = oi1;
                bool s2 = (v1 > o2) || (v1 == o2 && i1 < oi2);
                n2 = s2 ? v1 : o2; ni2 = s2 ? i1 : oi2;
            }
            v1 = n1; i1 = ni1; v2 = n2; i2 = ni2;
        }
        if (ln == 0) { top_idx[b * 2] = i1; top_idx[b * 2 + 1] = i2; }
    }
    if (t == 0) {       // graph: d2 -> knn -> An(LDS), cm, dropped
        float tot[10];
#pragma unroll
        for (int i = 0; i < 10; i++) tot[i] = sr[i][0] + sr[i][1] + sr[i][2] + sr[i][3];
        float n_[5] = {0.f, tot[0], tot[1], tot[2], tot[3]};
        float dd[5][5];
        dd[1][1] = tot[0]; dd[2][2] = tot[1]; dd[3][3] = tot[2]; dd[4][4] = tot[3];
        dd[1][2] = dd[2][1] = tot[4]; dd[1][3] = dd[3][1] = tot[5];
        dd[1][4] = dd[4][1] = tot[6]; dd[2][3] = dd[3][2] = tot[7];
        dd[2][4] = dd[4][2] = tot[8]; dd[3][4] = dd[4][3] = tot[9];
        float Q = tot[0] + tot[1] + tot[2] + tot[3];
        float d2[5][5];
        d2[0][0] = 0.f;
        for (int i = 1; i < 5; i++) {
            float v = Q + n_[i] - 2.f * dd[1][i];
            d2[0][i] = v; d2[i][0] = v;
        }
        for (int i = 1; i < 5; i++)
            for (int j = 1; j < 5; j++)
                d2[i][j] = (i == j) ? 0.f : (n_[i] + n_[j] - 2.f * dd[i][j]);
        int drp[5];
        for (int r = 0; r < 5; r++) {
            int dm = 0; float vm = d2[r][0];
            for (int ss = 1; ss < 5; ss++)
                if (d2[r][ss] >= vm) { vm = d2[r][ss]; dm = ss; }
            drp[r] = dm;
            dropped[b * 5 + r] = dm;
        }
        float dinv[5], Ah[5][5];
        for (int r = 0; r < 5; r++) {
            float dsum = 0.f;
            for (int ss = 0; ss < 5; ss++) {
                float a = ((ss != drp[r]) ? 1.f : 0.f) + ((ss == r) ? 1.f : 0.f);
                Ah[r][ss] = a; dsum += a;
            }
            dinv[r] = dsum > 0.f ? 1.f / sqrtf(dsum) : 0.f;
        }
        float colsum[5] = {0.f, 0.f, 0.f, 0.f, 0.f};
        for (int r = 0; r < 5; r++)
            for (int ss = 0; ss < 5; ss++) {
                float v = Ah[r][ss] * dinv[r] * dinv[ss];
                sAn[r * 5 + ss] = v;
                colsum[ss] += v;
            }
        for (int ss = 0; ss < 5; ss++) cm[b * 5 + ss] = colsum[ss] * 0.2f;
    }
    __syncthreads();

    // agg = An @ Xg
    for (int f = t; f < 1024; f += 256) {
        float a0 = sf[f];
        bool inq = f < 256;
        float v1 = 0.f, v2 = 0.f, v3 = 0.f, v4 = 0.f;
        if (inq) { v1 = sf[f]; v2 = sf[256 + f]; v3 = sf[512 + f]; v4 = sf[768 + f]; }
#pragma unroll
        for (int tt = 0; tt < 5; tt++) {
            float r = sAn[tt * 5] * a0;
            if (inq)
                r += sAn[tt * 5 + 1] * v1 + sAn[tt * 5 + 2] * v2 +
                     sAn[tt * 5 + 3] * v3 + sAn[tt * 5 + 4] * v4;
            agg[((size_t)b * 5 + tt) * 1024 + f] = r;
        }
    }
}

// ---------------- expert layer1 partials: h1part[fc][pair][t][h] (1024 blocks) ----------------
__global__ __launch_bounds__(128) void k_h1part(const float* __restrict__ agg,
                                                const float* __restrict__ w1,
                                                const int* __restrict__ top_idx,
                                                float* __restrict__ h1part) {
    int pair = blockIdx.x;              // 128
    int fc = blockIdx.y;                // 8 chunks of 128 f
    int hg = threadIdx.x;               // h = 4*hg
    int bsm = pair >> 1;
    int c = top_idx[pair];
    const f32x4* wv = (const f32x4*)(w1 + (size_t)c * 1024 * 512);
    const f32x4* av = (const f32x4*)(agg + (size_t)bsm * 5 * 1024);
    f32x4 acc[5];
#pragma unroll
    for (int t = 0; t < 5; t++) acc[t] = (f32x4)(0.f);
    int f0 = fc * 128;
#pragma unroll 2
    for (int f4 = 0; f4 < 32; f4++) {
        f32x4 a[5];
#pragma unroll
        for (int t = 0; t < 5; t++) a[t] = av[t * 256 + fc * 32 + f4];  // uniform
#pragma unroll
        for (int j = 0; j < 4; j++) {
            f32x4 w = wv[(size_t)(f0 + f4 * 4 + j) * 128 + hg];         // 16B coalesced
#pragma unroll
            for (int t = 0; t < 5; t++) acc[t] += a[t][j] * w;
        }
    }
    float* op = h1part + (((size_t)fc * 128 + pair) * 5) * 512;
#pragma unroll
    for (int t = 0; t < 5; t++)
        *(f32x4*)(op + t * 512 + 4 * hg) = acc[t];
}

// ---------------- expert2: fold + relu/cm + layer2 + b2 + @fin_w (512 thr) ----------------
__global__ __launch_bounds__(512) void k_expert2(const float* __restrict__ h1part,
                                                 const float* __restrict__ b1,
                                                 const float* __restrict__ w2,
                                                 const float* __restrict__ b2,
                                                 const float* __restrict__ finw,
                                                 const float* __restrict__ cm,
                                                 const int* __restrict__ top_idx,
                                                 float* __restrict__ M) {
    __shared__ float sp[512];
    __shared__ float sgq[8][256];
    __shared__ float sgg[256];
    int pair = blockIdx.x, t = threadIdx.x;
    int bsm = pair >> 1;
    int c = top_idx[pair];

    {   // fold: p[h] = sum_t cm[t]*relu(sum_fc part + b1), h = t
        float pv = 0.f;
#pragma unroll
        for (int tt = 0; tt < 5; tt++) {
            float sv = 0.f;
#pragma unroll
            for (int fc = 0; fc < 8; fc++)
                sv += h1part[(((size_t)fc * 128 + pair) * 5 + tt) * 512 + t];
            float hv = fmaxf(sv + b1[c * 512 + t], 0.f);
            pv = fmaf(cm[bsm * 5 + tt], hv, pv);
        }
        sp[t] = pv;
    }
    __syncthreads();

    {   // layer 2: og = t&63 (o-group of 4), hq = t>>6 (h-eighth of 64)
        int og = t & 63, hq = t >> 6;
        const f32x4* wv2 = (const f32x4*)(w2 + (size_t)c * 512 * 256);
        f32x4 acc2 = (f32x4)(0.f);
#pragma unroll 4
        for (int h = hq * 64; h < hq * 64 + 64; h++)
            acc2 += sp[h] * wv2[(size_t)h * 64 + og];            // sp broadcast
        *(f32x4*)&sgq[hq][og * 4] = acc2;
    }
    __syncthreads();
    if (t < 64) {
        f32x4 gsum = *(const f32x4*)&sgq[0][t * 4];
#pragma unroll
        for (int hq = 1; hq < 8; hq++) gsum += *(const f32x4*)&sgq[hq][t * 4];
        gsum += *(const f32x4*)&b2[c * 256 + 4 * t];
        *(f32x4*)&sgg[4 * t] = gsum;
    }
    __syncthreads();
    if (t < 80) {       // M[pair] = g @ fin_w
        float acc3 = 0.f;
        for (int o = 0; o < 256; o++) acc3 = fmaf(sgg[o], finw[o * 80 + t], acc3);
        M[pair * 80 + t] = acc3;
    }
}

// ---------------- final GCN + mean over k ----------------
__global__ __launch_bounds__(128) void k_out(const float* __restrict__ M,
                                             const float* __restrict__ finb,
                                             const int* __restrict__ dropped,
                                             float* __restrict__ out) {
    int b = blockIdx.x;
    int c = threadIdx.x;
    if (c >= 80) return;
    float bias = finb[c];
    float r = 0.f;
#pragma unroll
    for (int k = 0; k < 2; k++) {
        int n = b * 2 + k;
        float fin;
        if (n < 5) {
            float s = 0.f;
            for (int m = 0; m < 5; m++) {
                float a = ((m != dropped[63 * 5 + n]) ? 1.f : 0.f) + ((m == n) ? 1.f : 0.f);
                s += a * M[m * 80 + c];
            }
            fin = s * 0.2f + bias;
        } else {
            fin = M[n * 80 + c] + bias;
        }
        r += fin;
    }
    out[b * 80 + c] = r * 0.5f;
}

extern "C" void kernel_launch(void* const* d_in, const int* in_sizes, int n_in,
                              void* d_out, int out_size, void* d_ws, size_t ws_size,
                              hipStream_t stream) {
    const float* x       = (const float*)d_in[0];
    const float* conv1_w = (const float*)d_in[1];
    const float* conv1_b = (const float*)d_in[2];
    const float* conv2_w = (const float*)d_in[3];
    const float* conv2_b = (const float*)d_in[4];
    const float* fcf_w   = (const float*)d_in[5];
    const float* fcf_b   = (const float*)d_in[6];
    const float* fcc_w   = (const float*)d_in[7];
    const float* fcc_b   = (const float*)d_in[8];
    const float* gnn_w1  = (const float*)d_in[9];
    const float* gnn_b1  = (const float*)d_in[10];
    const float* gnn_w2  = (const float*)d_in[11];
    const float* gnn_b2  = (const float*)d_in[12];
    const float* fin_w   = (const float*)d_in[13];
    const float* fin_b   = (const float*)d_in[14];
    float* out = (float*)d_out;

    char* ws = (char*)d_ws;
    size_t off = 0;
    auto alloc = [&](size_t bytes) {
        void* pp = ws + off;
        off = (off + bytes + 255) & ~(size_t)255;
        return pp;
    };
    float* h1conv  = (float*)alloc((size_t)64 * 32 * 112 * 112 * 4);  // 102.8 MB
    float* wt1     = (float*)alloc(864 * 4);
    float* wt2     = (float*)alloc(18432 * 4);
    float* pooled  = (float*)alloc(4096 * 4);
    int*   top_idx = (int*)alloc(128 * 4);
    float* cm      = (float*)alloc(320 * 4);
    int*   dropped = (int*)alloc(320 * 4);
    float* agg     = (float*)alloc(327680 * 4);
    float* h1part  = (float*)alloc((size_t)2621440 * 4);   // 8*128*5*512 = 10.5 MB
    float* Mm      = (float*)alloc(10240 * 4);
    (void)ws_size; (void)in_sizes; (void)n_in; (void)out_size;

    k_prep<<<72, 256, 0, stream>>>(conv1_w, conv2_w, wt1, wt2, pooled);
    k_conv1<<<3136, 256, 0, stream>>>(x, wt1, conv1_b, h1conv);
    k_conv2gap<<<dim3(28, 64), 256, 0, stream>>>(h1conv, wt2, conv2_b, pooled);
    k_mid<<<64, 256, 0, stream>>>(pooled, fcf_w, fcf_b, fcc_w, fcc_b,
                                  top_idx, cm, dropped, agg);
    k_h1part<<<dim3(128, 8), 128, 0, stream>>>(agg, gnn_w1, top_idx, h1part);
    k_expert2<<<128, 512, 0, stream>>>(h1part, gnn_b1, gnn_w2, gnn_b2,
                                       fin_w, cm, top_idx, Mm);
    k_out<<<64, 128, 0, stream>>>(Mm, fin_b, dropped, out);
}

// Round 9
// 466.639 us; speedup vs baseline: 1.7346x; 1.0798x over previous
//
#include <hip/hip_runtime.h>

// YOLO_GNN on MI355X — round 9: tail attack. LDS-tiled conv1 (4 rows/block),
// f32x4 logits in mid, expert layer2 split (gpart 1024 blocks + Mfold).
// prep -> conv1tile -> conv2gap -> mid -> h1part(x8) -> gpart(x8) -> Mfold -> out.

typedef float f32x4 __attribute__((ext_vector_type(4)));

// ---------------- prep: zero pooled; transpose conv weights ----------------
__global__ void k_prep(const float* __restrict__ w1, const float* __restrict__ w2,
                       float* __restrict__ wt1, float* __restrict__ wt2,
                       float* __restrict__ pooled) {
    int i = blockIdx.x * 256 + threadIdx.x;
    if (i < 4096) pooled[i] = 0.f;
    if (i < 864) {            // conv1: 32 co x 27 k -> [k][co]
        int k = i >> 5, co = i & 31;
        wt1[i] = w1[co * 27 + k];
    }
    if (i < 18432) {          // conv2: ((ky*32+ci)*3+kx)*64+co
        int co = i & 63, tt = i >> 6;
        int kx = tt % 3, u = tt / 3;
        int ci = u & 31, ky = u >> 5;
        wt2[i] = w2[co * 288 + ci * 9 + ky * 3 + kx];
    }
}

// ---------------- conv1 tiled: 4 output rows per block, LDS-staged input ----------------
// Block = (oy4, b); stages x rows 8*oy4..8*oy4+8 (3 ci x 9 rows x 228 cols),
// computes 4x112 outputs (thread t -> px t and t+224), NCHW out.
__global__ __launch_bounds__(256) void k_conv1(const float* __restrict__ x,
                                               const float* __restrict__ wt1,
                                               const float* __restrict__ bias,
                                               float* __restrict__ out) {
    __shared__ float s[3][9][228];      // 24624 B
    int oy4 = blockIdx.x;               // 0..27
    int b = blockIdx.y;                 // 0..63
    int tid = threadIdx.x;
    const float* xb = x + (size_t)b * 3 * 224 * 224;

    // stage: 3*9*57 = 1539 float4 items, coalesced
    for (int i = tid; i < 1539; i += 256) {
        int ci = i / 513, rem = i - ci * 513;
        int r = rem / 57, f4 = rem - r * 57;
        int iy = 8 * oy4 + r;
        float4 v = make_float4(0.f, 0.f, 0.f, 0.f);
        if (iy < 224 && f4 < 56)        // cols 224..227 stay zero (SAME pad hi)
            v = *(const float4*)&xb[((size_t)ci * 224 + iy) * 224 + 4 * f4];
        *(float4*)&s[ci][r][4 * f4] = v;
    }
    __syncthreads();

    // compute: outputs j = tid, tid+224 (224 active threads, 2 px each)
#pragma unroll 1
    for (int rep = 0; rep < 2; rep++) {
        int j = tid + rep * 224;
        if (tid < 224 && j < 448) {
            int ry = j / 112, ox = j - ry * 112;    // ry 0..3
            float acc[32];
#pragma unroll
            for (int co = 0; co < 32; co++) acc[co] = 0.f;
#pragma unroll
            for (int ky = 0; ky < 3; ky++) {
                int r = 2 * ry + ky;
#pragma unroll
                for (int kx = 0; kx < 3; kx++) {
#pragma unroll
                    for (int ci = 0; ci < 3; ci++) {
                        float v = s[ci][r][2 * ox + kx];
                        const float* w = wt1 + ((ci * 3 + ky) * 3 + kx) * 32;  // uniform
#pragma unroll
                        for (int co = 0; co < 32; co++) acc[co] = fmaf(v, w[co], acc[co]);
                    }
                }
            }
            int oy = 4 * oy4 + ry;
            float* ob = out + (size_t)b * 32 * 12544 + oy * 112 + ox;
#pragma unroll
            for (int co = 0; co < 32; co++) {
                float rr = acc[co] + bias[co];
                ob[(size_t)co * 12544] = rr > 0.f ? rr : 0.f;
            }
        }
    }
}

// ---------------- conv2 (32->64, s2) + ReLU + GAP: 2 rows/block, 16-ch split staging --------
__global__ __launch_bounds__(256) void k_conv2gap(const float* __restrict__ h1,
                                                  const float* __restrict__ wt2,
                                                  const float* __restrict__ b2,
                                                  float* __restrict__ pooled) {
    __shared__ float s[16][5][116];     // 37120 B
    int oy2 = blockIdx.x;               // 0..27
    int b = blockIdx.y;                 // 0..63
    int tid = threadIdx.x;

    int q = __builtin_amdgcn_readfirstlane((int)(tid >> 6));
    int lane = tid & 63;
    bool pvld = lane < 56;
    int opx = pvld ? lane : 55;
    float acc[2][16];
#pragma unroll
    for (int ry = 0; ry < 2; ry++)
#pragma unroll
        for (int j = 0; j < 16; j++) acc[ry][j] = 0.f;

#pragma unroll 1
    for (int cp = 0; cp < 2; cp++) {
        if (cp) __syncthreads();
        for (int i = tid; i < 2320; i += 256) {
            int row = i / 29, f4 = i - row * 29;
            int ci = row / 5, r = row - ci * 5;
            int iy = 4 * oy2 + r;
            float4 v = make_float4(0.f, 0.f, 0.f, 0.f);
            if (f4 < 28 && iy < 112)
                v = *(const float4*)&h1[(((size_t)b * 32 + cp * 16 + ci) * 112 + iy) * 112 + 4 * f4];
            *(float4*)&s[ci][r][4 * f4] = v;
        }
        __syncthreads();

#pragma unroll
        for (int ky = 0; ky < 3; ky++) {
#pragma unroll 4
            for (int ci = 0; ci < 16; ci++) {
                const float* w = wt2 + ((ky * 32 + cp * 16 + ci) * 3) * 64 + q * 16;  // uniform
#pragma unroll
                for (int ry = 0; ry < 2; ry++) {
                    int r = 2 * ry + ky;
                    float2 v01 = *(const float2*)&s[ci][r][2 * opx];
                    float v2 = s[ci][r][2 * opx + 2];
#pragma unroll
                    for (int j = 0; j < 16; j++) acc[ry][j] = fmaf(v01.x, w[j], acc[ry][j]);
#pragma unroll
                    for (int j = 0; j < 16; j++) acc[ry][j] = fmaf(v01.y, w[64 + j], acc[ry][j]);
#pragma unroll
                    for (int j = 0; j < 16; j++) acc[ry][j] = fmaf(v2, w[128 + j], acc[ry][j]);
                }
            }
        }
    }
#pragma unroll
    for (int j = 0; j < 16; j++) {
        float bj = b2[q * 16 + j];
        float rv = 0.f;
        if (pvld)
            rv = fmaxf(acc[0][j] + bj, 0.f) + fmaxf(acc[1][j] + bj, 0.f);
#pragma unroll
        for (int sft = 32; sft > 0; sft >>= 1) rv += __shfl_xor(rv, sft);
        if (lane == 0) atomicAdd(&pooled[b * 64 + q * 16 + j], rv);
    }
}

// ---------------- mid: feats -> logits(f32x4) -> top2 -> graph -> agg ----------------
__global__ __launch_bounds__(256) void k_mid(const float* __restrict__ pooled,
                                             const float* __restrict__ fcf_w,
                                             const float* __restrict__ fcf_b,
                                             const float* __restrict__ fcc_w,
                                             const float* __restrict__ fcc_b,
                                             int* __restrict__ top_idx,
                                             float* __restrict__ cm,
                                             int* __restrict__ dropped,
                                             float* __restrict__ agg) {
    __shared__ __align__(16) float sf[1024];
    __shared__ float slog[2][80];
    __shared__ float sr[10][4];
    __shared__ float sAn[25];
    int b = blockIdx.x, t = threadIdx.x;

    {   // feats = relu(pooled/3136 @ fcf_w + fcf_b)
        float acc[4];
#pragma unroll
        for (int j = 0; j < 4; j++) acc[j] = fcf_b[t + j * 256];
        for (int cc = 0; cc < 64; cc++) {
            float pv = pooled[b * 64 + cc] * (1.f / 3136.f);    // uniform
#pragma unroll
            for (int j = 0; j < 4; j++)
                acc[j] = fmaf(pv, fcf_w[cc * 1024 + t + j * 256], acc[j]);
        }
#pragma unroll
        for (int j = 0; j < 4; j++) sf[t + j * 256] = fmaxf(acc[j], 0.f);
    }
    __syncthreads();

    if (t < 160) {      // logits halves, f32x4 LDS reads: 128 iters
        int c = t % 80, half = t / 80;
        float acc = half ? 0.f : fcc_b[c];
        int fb = half * 512;
        for (int f4 = 0; f4 < 128; f4++) {
            f32x4 fr = *(const f32x4*)&sf[fb + f4 * 4];
#pragma unroll
            for (int j = 0; j < 4; j++)
                acc = fmaf(fr[j], fcc_w[(fb + f4 * 4 + j) * 80 + c], acc);
        }
        slog[half][c] = acc;
    }
    {   // graph quarter norms/dots
        float q1 = sf[t], q2 = sf[256 + t], q3 = sf[512 + t], q4 = sf[768 + t];
        float part[10] = {q1 * q1, q2 * q2, q3 * q3, q4 * q4,
                          q1 * q2, q1 * q3, q1 * q4, q2 * q3, q2 * q4, q3 * q4};
        int lane = t & 63, wid = t >> 6;
#pragma unroll
        for (int i = 0; i < 10; i++) {
            float r = part[i];
#pragma unroll
            for (int sft = 32; sft > 0; sft >>= 1) r += __shfl_xor(r, sft);
            if (lane == 0) sr[i][wid] = r;
        }
    }
    __syncthreads();

    if (t < 64) {       // top2 via wave butterfly (tie: lower index)
        int ln = t;
        float vA = slog[0][ln] + slog[1][ln];
        int iA = ln;
        bool hasB = ln < 16;
        float vB = hasB ? slog[0][64 + ln] + slog[1][64 + ln] : -3.4e38f;
        int iB = hasB ? 64 + ln : 0x7fffffff;
        float v1, v2; int i1, i2;
        if (vB > vA) { v1 = vB; i1 = iB; v2 = vA; i2 = iA; }
        else         { v1 = vA; i1 = iA; v2 = vB; i2 = iB; }
#pragma unroll
        for (int m = 1; m < 64; m <<= 1) {
            float o1 = __shfl_xor(v1, m), o2 = __shfl_xor(v2, m);
            int oi1 = __shfl_xor(i1, m), oi2 = __shfl_xor(i2, m);
            bool selfWins = (v1 > o1) || (v1 == o1 && i1 < oi1);
            float n1, n2; int ni1, ni2;
            if (selfWins) {
                n1 = v1; ni1 = i1;
                bool s2 = (v2 > o1) || (v2 == o1 && i2 < oi1);
                n2 = s2 ? v2 : o1; ni2 = s2 ? i2 : oi1;
            } else {
                n1 = o1; ni1 = oi1;
                bool s2 = (v1 > o2) || (v1 == o2 && i1 < oi2);
                n2 = s2 ? v1 : o2; ni2 = s2 ? i1 : oi2;
            }
            v1 = n1; i1 = ni1; v2 = n2; i2 = ni2;
        }
        if (ln == 0) { top_idx[b * 2] = i1; top_idx[b * 2 + 1] = i2; }
    }
    if (t == 0) {       // graph: d2 -> knn -> An(LDS), cm, dropped
        float tot[10];
#pragma unroll
        for (int i = 0; i < 10; i++) tot[i] = sr[i][0] + sr[i][1] + sr[i][2] + sr[i][3];
        float n_[5] = {0.f, tot[0], tot[1], tot[2], tot[3]};
        float dd[5][5];
        dd[1][1] = tot[0]; dd[2][2] = tot[1]; dd[3][3] = tot[2]; dd[4][4] = tot[3];
        dd[1][2] = dd[2][1] = tot[4]; dd[1][3] = dd[3][1] = tot[5];
        dd[1][4] = dd[4][1] = tot[6]; dd[2][3] = dd[3][2] = tot[7];
        dd[2][4] = dd[4][2] = tot[8]; dd[3][4] = dd[4][3] = tot[9];
        float Q = tot[0] + tot[1] + tot[2] + tot[3];
        float d2[5][5];
        d2[0][0] = 0.f;
        for (int i = 1; i < 5; i++) {
            float v = Q + n_[i] - 2.f * dd[1][i];
            d2[0][i] = v; d2[i][0] = v;
        }
        for (int i = 1; i < 5; i++)
            for (int j = 1; j < 5; j++)
                d2[i][j] = (i == j) ? 0.f : (n_[i] + n_[j] - 2.f * dd[i][j]);
        int drp[5];
        for (int r = 0; r < 5; r++) {
            int dm = 0; float vm = d2[r][0];
            for (int ss = 1; ss < 5; ss++)
                if (d2[r][ss] >= vm) { vm = d2[r][ss]; dm = ss; }
            drp[r] = dm;
            dropped[b * 5 + r] = dm;
        }
        float dinv[5], Ah[5][5];
        for (int r = 0; r < 5; r++) {
            float dsum = 0.f;
            for (int ss = 0; ss < 5; ss++) {
                float a = ((ss != drp[r]) ? 1.f : 0.f) + ((ss == r) ? 1.f : 0.f);
                Ah[r][ss] = a; dsum += a;
            }
            dinv[r] = dsum > 0.f ? 1.f / sqrtf(dsum) : 0.f;
        }
        float colsum[5] = {0.f, 0.f, 0.f, 0.f, 0.f};
        for (int r = 0; r < 5; r++)
            for (int ss = 0; ss < 5; ss++) {
                float v = Ah[r][ss] * dinv[r] * dinv[ss];
                sAn[r * 5 + ss] = v;
                colsum[ss] += v;
            }
        for (int ss = 0; ss < 5; ss++) cm[b * 5 + ss] = colsum[ss] * 0.2f;
    }
    __syncthreads();

    // agg = An @ Xg
    for (int f = t; f < 1024; f += 256) {
        float a0 = sf[f];
        bool inq = f < 256;
        float v1 = 0.f, v2 = 0.f, v3 = 0.f, v4 = 0.f;
        if (inq) { v1 = sf[f]; v2 = sf[256 + f]; v3 = sf[512 + f]; v4 = sf[768 + f]; }
#pragma unroll
        for (int tt = 0; tt < 5; tt++) {
            float r = sAn[tt * 5] * a0;
            if (inq)
                r += sAn[tt * 5 + 1] * v1 + sAn[tt * 5 + 2] * v2 +
                     sAn[tt * 5 + 3] * v3 + sAn[tt * 5 + 4] * v4;
            agg[((size_t)b * 5 + tt) * 1024 + f] = r;
        }
    }
}

// ---------------- expert layer1 partials: h1part[fc][pair][t][h] (1024 blocks) ----------------
__global__ __launch_bounds__(128) void k_h1part(const float* __restrict__ agg,
                                                const float* __restrict__ w1,
                                                const int* __restrict__ top_idx,
                                                float* __restrict__ h1part) {
    int pair = blockIdx.x;              // 128
    int fc = blockIdx.y;                // 8 chunks of 128 f
    int hg = threadIdx.x;               // h = 4*hg
    int bsm = pair >> 1;
    int c = top_idx[pair];
    const f32x4* wv = (const f32x4*)(w1 + (size_t)c * 1024 * 512);
    const f32x4* av = (const f32x4*)(agg + (size_t)bsm * 5 * 1024);
    f32x4 acc[5];
#pragma unroll
    for (int t = 0; t < 5; t++) acc[t] = (f32x4)(0.f);
    int f0 = fc * 128;
#pragma unroll 2
    for (int f4 = 0; f4 < 32; f4++) {
        f32x4 a[5];
#pragma unroll
        for (int t = 0; t < 5; t++) a[t] = av[t * 256 + fc * 32 + f4];  // uniform
#pragma unroll
        for (int j = 0; j < 4; j++) {
            f32x4 w = wv[(size_t)(f0 + f4 * 4 + j) * 128 + hg];         // 16B coalesced
#pragma unroll
            for (int t = 0; t < 5; t++) acc[t] += a[t][j] * w;
        }
    }
    float* op = h1part + (((size_t)fc * 128 + pair) * 5) * 512;
#pragma unroll
    for (int t = 0; t < 5; t++)
        *(f32x4*)(op + t * 512 + 4 * hg) = acc[t];
}

// ---------------- gpart: fold h-slice + layer2 over h-chunk: gpart[hc][pair][o] ------------
// Block = (pair, hc of 8 x 64 h); 64 threads.
__global__ __launch_bounds__(64) void k_gpart(const float* __restrict__ h1part,
                                              const float* __restrict__ b1,
                                              const float* __restrict__ w2,
                                              const float* __restrict__ cm,
                                              const int* __restrict__ top_idx,
                                              float* __restrict__ gpart) {
    __shared__ float sp[64];
    int pair = blockIdx.x, hc = blockIdx.y;
    int t = threadIdx.x;
    int bsm = pair >> 1;
    int c = top_idx[pair];
    int h = hc * 64 + t;

    {   // fold for my h: p[h] = sum_t cm*relu(sum_fc part + b1)
        float pv = 0.f;
#pragma unroll
        for (int tt = 0; tt < 5; tt++) {
            float sv = 0.f;
#pragma unroll
            for (int fc = 0; fc < 8; fc++)
                sv += h1part[(((size_t)fc * 128 + pair) * 5 + tt) * 512 + h];
            float hv = fmaxf(sv + b1[c * 512 + h], 0.f);
            pv = fmaf(cm[bsm * 5 + tt], hv, pv);
        }
        sp[t] = pv;
    }
    __syncthreads();

    {   // layer2: og = t, f32x4 over the 64 h of this chunk
        const f32x4* wv2 = (const f32x4*)(w2 + (size_t)c * 512 * 256);
        f32x4 acc = (f32x4)(0.f);
#pragma unroll 4
        for (int hh = 0; hh < 64; hh++)
            acc += sp[hh] * wv2[(size_t)(hc * 64 + hh) * 64 + t];   // sp broadcast
        *(f32x4*)&gpart[((size_t)hc * 128 + pair) * 256 + 4 * t] = acc;
    }
}

// ---------------- Mfold: g = sum_hc gpart + b2; M = g @ fin_w ----------------
__global__ __launch_bounds__(128) void k_Mfold(const float* __restrict__ gpart,
                                               const float* __restrict__ b2,
                                               const float* __restrict__ finw,
                                               const int* __restrict__ top_idx,
                                               float* __restrict__ M) {
    __shared__ __align__(16) float sgg[256];
    int n = blockIdx.x, t = threadIdx.x;
    int c = top_idx[n];
#pragma unroll
    for (int rep = 0; rep < 2; rep++) {
        int o = t + rep * 128;
        float gg = b2[c * 256 + o];
#pragma unroll
        for (int hc = 0; hc < 8; hc++)
            gg += gpart[((size_t)hc * 128 + n) * 256 + o];
        sgg[o] = gg;
    }
    __syncthreads();
    if (t < 80) {
        float acc = 0.f;
        for (int o4 = 0; o4 < 64; o4++) {
            f32x4 gr = *(const f32x4*)&sgg[o4 * 4];
#pragma unroll
            for (int j = 0; j < 4; j++)
                acc = fmaf(gr[j], finw[(o4 * 4 + j) * 80 + t], acc);
        }
        M[n * 80 + t] = acc;
    }
}

// ---------------- final GCN + mean over k ----------------
__global__ __launch_bounds__(128) void k_out(const float* __restrict__ M,
                                             const float* __restrict__ finb,
                                             const int* __restrict__ dropped,
                                             float* __restrict__ out) {
    int b = blockIdx.x;
    int c = threadIdx.x;
    if (c >= 80) return;
    float bias = finb[c];
    float r = 0.f;
#pragma unroll
    for (int k = 0; k < 2; k++) {
        int n = b * 2 + k;
        float fin;
        if (n < 5) {
            float s = 0.f;
            for (int m = 0; m < 5; m++) {
                float a = ((m != dropped[63 * 5 + n]) ? 1.f : 0.f) + ((m == n) ? 1.f : 0.f);
                s += a * M[m * 80 + c];
            }
            fin = s * 0.2f + bias;
        } else {
            fin = M[n * 80 + c] + bias;
        }
        r += fin;
    }
    out[b * 80 + c] = r * 0.5f;
}

extern "C" void kernel_launch(void* const* d_in, const int* in_sizes, int n_in,
                              void* d_out, int out_size, void* d_ws, size_t ws_size,
                              hipStream_t stream) {
    const float* x       = (const float*)d_in[0];
    const float* conv1_w = (const float*)d_in[1];
    const float* conv1_b = (const float*)d_in[2];
    const float* conv2_w = (const float*)d_in[3];
    const float* conv2_b = (const float*)d_in[4];
    const float* fcf_w   = (const float*)d_in[5];
    const float* fcf_b   = (const float*)d_in[6];
    const float* fcc_w   = (const float*)d_in[7];
    const float* fcc_b   = (const float*)d_in[8];
    const float* gnn_w1  = (const float*)d_in[9];
    const float* gnn_b1  = (const float*)d_in[10];
    const float* gnn_w2  = (const float*)d_in[11];
    const float* gnn_b2  = (const float*)d_in[12];
    const float* fin_w   = (const float*)d_in[13];
    const float* fin_b   = (const float*)d_in[14];
    float* out = (float*)d_out;

    char* ws = (char*)d_ws;
    size_t off = 0;
    auto alloc = [&](size_t bytes) {
        void* pp = ws + off;
        off = (off + bytes + 255) & ~(size_t)255;
        return pp;
    };
    float* h1conv  = (float*)alloc((size_t)64 * 32 * 112 * 112 * 4);  // 102.8 MB
    float* wt1     = (float*)alloc(864 * 4);
    float* wt2     = (float*)alloc(18432 * 4);
    float* pooled  = (float*)alloc(4096 * 4);
    int*   top_idx = (int*)alloc(128 * 4);
    float* cm      = (float*)alloc(320 * 4);
    int*   dropped = (int*)alloc(320 * 4);
    float* agg     = (float*)alloc(327680 * 4);
    float* h1part  = (float*)alloc((size_t)2621440 * 4);   // 8*128*5*512 = 10.5 MB
    float* gpart   = (float*)alloc(262144 * 4);            // 8*128*256 = 1 MB
    float* Mm      = (float*)alloc(10240 * 4);
    (void)ws_size; (void)in_sizes; (void)n_in; (void)out_size;

    k_prep<<<72, 256, 0, stream>>>(conv1_w, conv2_w, wt1, wt2, pooled);
    k_conv1<<<dim3(28, 64), 256, 0, stream>>>(x, wt1, conv1_b, h1conv);
    k_conv2gap<<<dim3(28, 64), 256, 0, stream>>>(h1conv, wt2, conv2_b, pooled);
    k_mid<<<64, 256, 0, stream>>>(pooled, fcf_w, fcf_b, fcc_w, fcc_b,
                                  top_idx, cm, dropped, agg);
    k_h1part<<<dim3(128, 8), 128, 0, stream>>>(agg, gnn_w1, top_idx, h1part);
    k_gpart<<<dim3(128, 8), 64, 0, stream>>>(h1part, gnn_b1, gnn_w2, cm, top_idx, gpart);
    k_Mfold<<<128, 128, 0, stream>>>(gpart, gnn_b2, fin_w, top_idx, Mm);
    k_out<<<64, 128, 0, stream>>>(Mm, fin_b, dropped, out);
}